// Round 7
// baseline (1292.617 us; speedup 1.0000x reference)
//
#include <hip/hip_runtime.h>
#include <stdint.h>

typedef unsigned short ushort_t;

#define B_   128
#define S_   50
#define D_   128
#define ALPHA_ 0.2f

__device__ __forceinline__ float bf2f(ushort_t u){
  return __uint_as_float(((uint32_t)u) << 16);
}
__device__ __forceinline__ ushort_t f2bf(float f){
  uint32_t x = __float_as_uint(f);
  x = (x + 0x7fffu + ((x >> 16) & 1u)) >> 16;
  return (ushort_t)x;
}
__device__ __forceinline__ float leaky(float x){ return x >= 0.f ? x : ALPHA_*x; }

// ---- detect: are float inputs bf16-packed (flag=1) or f32 (flag=0)? -------
__global__ void detect_kernel(const uint32_t* __restrict__ emb_raw, int* __restrict__ flag){
  if (threadIdx.x == 0 && blockIdx.x == 0){
    int ok = 1;
    for (int i = 0; i < 64; i++){
      uint32_t lo = emb_raw[i] & 0xffffu;
      uint32_t ex = (lo >> 7) & 0xFFu;
      if (!(lo == 0u || (ex >= 64u && ex <= 126u))) ok = 0;
    }
    *flag = ok;
  }
}

// ---- convert: src (bf16-packed or f32 per flag) -> dst bf16 ---------------
__global__ void cvt_kernel(const void* __restrict__ src, ushort_t* __restrict__ dst,
                           int n, const int* __restrict__ flag){
  int i = blockIdx.x*256 + threadIdx.x;
  if (i >= n) return;
  if (*flag){
    dst[i] = ((const ushort_t*)src)[i];
  } else {
    dst[i] = f2bf(((const float*)src)[i]);
  }
}

// ---- sess: masked mean of item embeddings -> f32 (B,D) --------------------
__global__ void sess_kernel(const int* __restrict__ item, const int* __restrict__ mask,
                            const ushort_t* __restrict__ emb, float* __restrict__ sess){
  int b = blockIdx.x, d = threadIdx.x;
  float acc = 0.f, den = 0.f;
  for (int s = 0; s < S_; s++){
    float fm = (float)mask[b*S_ + s];
    int id = item[b*S_ + s];
    acc += fm * bf2f(emb[(size_t)id*D_ + d]);
    den += fm;
  }
  sess[b*D_ + d] = acc / den;
}

// ---- local attention: one 128-thread block per (b,i) ----------------------
__global__ void local_kernel(const int* __restrict__ inputs, const int* __restrict__ adj,
                             const ushort_t* __restrict__ emb, const ushort_t* __restrict__ a_local,
                             ushort_t* __restrict__ hlb){
  int bi = blockIdx.x;               // b*50+i
  int b  = bi / S_;
  int i  = bi - b*S_;
  int t  = threadIdx.x;              // 0..127
  const int* ids = inputs + b*S_;
  __shared__ float es[S_];
  __shared__ float att[S_];
  if (t < S_){
    int kk = adj[(size_t)bi*S_ + t];
    float ev = -9.0e15f;
    if (kk != 0){
      const ushort_t* hi = emb + (size_t)ids[i]*D_;
      const ushort_t* hj = emb + (size_t)ids[t]*D_;
      const ushort_t* al = a_local + (kk-1)*D_;
      float acc = 0.f;
      for (int d = 0; d < D_; d++)
        acc += bf2f(hi[d]) * bf2f(hj[d]) * bf2f(al[d]);
      ev = leaky(acc);
    }
    es[t] = ev;
  }
  __syncthreads();
  if (t == 0){
    float mx = -__builtin_inff();
    for (int j = 0; j < S_; j++) mx = fmaxf(mx, es[j]);
    float s = 0.f;
    for (int j = 0; j < S_; j++){ att[j] = __expf(es[j] - mx); s += att[j]; }
    float inv = 1.f / s;
    for (int j = 0; j < S_; j++) att[j] *= inv;
  }
  __syncthreads();
  float o = 0.f;
  for (int j = 0; j < S_; j++)
    o += att[j] * bf2f(emb[(size_t)ids[j]*D_ + t]);
  hlb[(size_t)bi*D_ + t] = f2bf(o);
}

// ---- score: one 128-thread block per row; thread = e ----------------------
// MODE0: RPB=600,  neigh = emb[neigh1[row]]
// MODE1: RPB=1200, neigh = emb[adj_all[neigh1[row>>1]*2 + (row&1)]]
// MODE2: RPB=600,  neigh = out1[row]
template<int MODE>
__global__ void score_dumb(const float* __restrict__ sess, const ushort_t* __restrict__ emb,
                           const int* __restrict__ neigh1, const int* __restrict__ adj_all,
                           const ushort_t* __restrict__ out1,
                           const ushort_t* __restrict__ w1, const ushort_t* __restrict__ w2,
                           float* __restrict__ score){
  int row = blockIdx.x, e = threadIdx.x;
  const int RPB = (MODE == 1) ? 1200 : 600;
  int b = row / RPB;
  const ushort_t* nptr;
  if (MODE == 0)      nptr = emb  + (size_t)neigh1[row]*D_;
  else if (MODE == 1) nptr = emb  + (size_t)adj_all[(size_t)neigh1[row>>1]*2 + (row&1)]*D_;
  else                nptr = out1 + (size_t)row*D_;
  const float* sb = sess + (size_t)b*D_;
  float acc = 0.f;
  for (int d = 0; d < D_; d++){
    float x = sb[d] * bf2f(nptr[d]);
    acc += x * bf2f(w1[d*D_ + e]);
  }
  acc = leaky(acc) * bf2f(w2[e]);
  __shared__ float red[D_];
  red[e] = acc;
  __syncthreads();
  for (int s = 64; s > 0; s >>= 1){
    if (e < s) red[e] += red[e + s];
    __syncthreads();
  }
  if (e == 0) score[row] = red[0];
}

// ---- out: one 128-thread block per row; thread = e ------------------------
// MODE0: K=12, self=emb[idx[row]], neigh=emb[nbr[row*12+k]]        -> outb
// MODE1: K=2,  self=emb[nbr[row]], neigh=emb[adj_all[nbr[row]*2+k]] -> outb
// MODE2: K=12, self=selfsrc[row],  neigh=out1[row*12+k]            -> outf (f32, +addsrc)
template<int MODE>
__global__ void out_dumb(const float* __restrict__ score, const int* __restrict__ idx,
                         const int* __restrict__ nbr, const int* __restrict__ adj_all,
                         const ushort_t* __restrict__ emb, const ushort_t* __restrict__ out1,
                         const ushort_t* __restrict__ selfsrc,
                         const ushort_t* __restrict__ w3, const ushort_t* __restrict__ bias,
                         const ushort_t* __restrict__ addsrc,
                         ushort_t* __restrict__ outb, float* __restrict__ outf){
  const int K = (MODE == 1) ? 2 : 12;
  int row = blockIdx.x, e = threadIdx.x;
  __shared__ float att[12];
  __shared__ float sa[2*D_];          // self | agg
  if (e == 0){
    const float* sc = score + (size_t)row*K;
    float mx = -__builtin_inff();
    for (int k = 0; k < K; k++) mx = fmaxf(mx, sc[k]);
    float s = 0.f;
    for (int k = 0; k < K; k++){ att[k] = __expf(sc[k] - mx); s += att[k]; }
    float inv = 1.f / s;
    for (int k = 0; k < K; k++) att[k] *= inv;
  }
  __syncthreads();
  {
    int d = e;
    float sv;
    if (MODE == 0)      sv = bf2f(emb[(size_t)idx[row]*D_ + d]);
    else if (MODE == 1) sv = bf2f(emb[(size_t)nbr[row]*D_ + d]);
    else                sv = bf2f(selfsrc[(size_t)row*D_ + d]);
    sa[d] = sv;
    float g = 0.f;
    for (int k = 0; k < K; k++){
      float nv;
      if (MODE == 0)      nv = bf2f(emb[(size_t)nbr[row*12 + k]*D_ + d]);
      else if (MODE == 1) nv = bf2f(emb[(size_t)adj_all[(size_t)nbr[row]*2 + k]*D_ + d]);
      else                nv = bf2f(out1[(size_t)(row*12 + k)*D_ + d]);
      g += att[k] * nv;
    }
    sa[D_ + d] = g;
  }
  __syncthreads();
  float acc = bf2f(bias[e]);
  for (int d = 0; d < 2*D_; d++)
    acc += sa[d] * bf2f(w3[d*D_ + e]);
  float v = fmaxf(acc, 0.f);
  if (MODE == 2){
    v += bf2f(addsrc[(size_t)row*D_ + e]);
    outf[(size_t)row*D_ + e] = v;              // FINAL OUTPUT: f32 storage
  } else {
    outb[(size_t)row*D_ + e] = f2bf(v);        // intermediates: bf16 in ws
  }
}

extern "C" void kernel_launch(void* const* d_in, const int* in_sizes, int n_in,
                              void* d_out, int out_size, void* d_ws, size_t ws_size,
                              hipStream_t stream) {
  const int* inputs    = (const int*)d_in[0];
  const int* adj       = (const int*)d_in[1];
  const int* mask_item = (const int*)d_in[2];
  const int* item      = (const int*)d_in[3];
  const int* first_adj = (const int*)d_in[4];    // neigh1 (B,600)
  const int* adj_all   = (const int*)d_in[5];    // (50000,2)

  // ---- ws layout ----
  char* ws = (char*)d_ws;
  size_t o = 0;
  int*      flag   = (int*)(ws + o);      o += 64;
  ushort_t* emb_b  = (ushort_t*)(ws + o); o += 12800000;  // 50000*128 bf16
  ushort_t* alocb  = (ushort_t*)(ws + o); o += 1024;      // 4*128
  ushort_t* gw1b   = (ushort_t*)(ws + o); o += 65536;     // 2*128*128
  ushort_t* gw2b   = (ushort_t*)(ws + o); o += 512;       // 2*128
  ushort_t* gw3b   = (ushort_t*)(ws + o); o += 131072;    // 2*256*128
  ushort_t* gbb    = (ushort_t*)(ws + o); o += 512;       // 2*128
  float*    sess_f = (float*)(ws + o);    o += 65536;     // 128*128 f32
  ushort_t* hlb    = (ushort_t*)(ws + o); o += 1638400;   // 6400*128 bf16
  size_t fixed = o;
  // variable: out1c CHB*153600 + o0c CHB*12800 + score CHB*4800 = CHB*171200
  int CHB = 16;
  if      (ws_size >= fixed + (size_t)128*171200) CHB = 128;
  else if (ws_size >= fixed + (size_t)64 *171200) CHB = 64;
  else if (ws_size >= fixed + (size_t)32 *171200) CHB = 32;
  ushort_t* out1c = (ushort_t*)(ws + o);  o += (size_t)CHB*153600;
  ushort_t* o0c   = (ushort_t*)(ws + o);  o += (size_t)CHB*12800;
  float*    score = (float*)(ws + o);

  float* outp = (float*)d_out;   // OUTPUT IS F32 STORAGE

  // ---- dtype normalize ----
  detect_kernel<<<1, 64, 0, stream>>>((const uint32_t*)d_in[6], flag);
  cvt_kernel<<<(6400000+255)/256, 256, 0, stream>>>(d_in[6],  emb_b, 6400000, flag);
  cvt_kernel<<<(512+255)/256,     256, 0, stream>>>(d_in[7],  alocb, 512,     flag);
  cvt_kernel<<<(32768+255)/256,   256, 0, stream>>>(d_in[8],  gw1b,  32768,   flag);
  cvt_kernel<<<(256+255)/256,     256, 0, stream>>>(d_in[9],  gw2b,  256,     flag);
  cvt_kernel<<<(65536+255)/256,   256, 0, stream>>>(d_in[10], gw3b,  65536,   flag);
  cvt_kernel<<<(256+255)/256,     256, 0, stream>>>(d_in[11], gbb,   256,     flag);

  sess_kernel <<<B_, 128, 0, stream>>>(item, mask_item, emb_b, sess_f);
  local_kernel<<<B_*S_, 128, 0, stream>>>(inputs, adj, emb_b, alocb, hlb);

  int nchunk = B_ / CHB;
  for (int c = 0; c < nchunk; c++){
    int b0 = c * CHB;
    const float* sessc = sess_f + (size_t)b0 * D_;
    const int*   fadj  = first_adj + (size_t)b0 * 600;
    ushort_t*    hlc   = hlb  + (size_t)b0 * 50 * D_;
    float*       outc  = outp + (size_t)b0 * 50 * D_;

    // call A: hop-0 weights; scores CHB*600; out CHB*50 -> o0c (bf16)
    score_dumb<0><<<CHB*600, 128, 0, stream>>>(sessc, emb_b, fadj, adj_all, out1c,
                                               gw1b, gw2b, score);
    out_dumb<0><<<CHB*50, 128, 0, stream>>>(score, inputs + b0*50, fadj, adj_all,
                                            emb_b, out1c, emb_b, gw3b, gbb,
                                            nullptr, o0c, nullptr);
    // call B: hop-0 weights; scores CHB*1200; out CHB*600 -> out1c (bf16)
    score_dumb<1><<<CHB*1200, 128, 0, stream>>>(sessc, emb_b, fadj, adj_all, out1c,
                                                gw1b, gw2b, score);
    out_dumb<1><<<CHB*600, 128, 0, stream>>>(score, nullptr, fadj, adj_all,
                                             emb_b, out1c, emb_b, gw3b, gbb,
                                             nullptr, out1c, nullptr);
    // call C: hop-1 weights; scores CHB*600; out CHB*50 -> d_out (f32, +h_local)
    score_dumb<2><<<CHB*600, 128, 0, stream>>>(sessc, emb_b, fadj, adj_all, out1c,
                                               gw1b + 16384, gw2b + 128, score);
    out_dumb<2><<<CHB*50, 128, 0, stream>>>(score, nullptr, fadj, adj_all,
                                            emb_b, out1c, o0c, gw3b + 32768, gbb + 128,
                                            hlc, nullptr, outc);
  }
}

// Round 8
// 866.103 us; speedup vs baseline: 1.4925x; 1.4925x over previous
//
#include <hip/hip_runtime.h>
#include <stdint.h>

typedef unsigned short ushort_t;

#define B_   128
#define S_   50
#define D_   128
#define ALPHA_ 0.2f

__device__ __forceinline__ float bf2f(ushort_t u){
  return __uint_as_float(((uint32_t)u) << 16);
}
__device__ __forceinline__ ushort_t f2bf(float f){
  uint32_t x = __float_as_uint(f);
  x = (x + 0x7fffu + ((x >> 16) & 1u)) >> 16;
  return (ushort_t)x;
}
__device__ __forceinline__ float leaky(float x){ return x >= 0.f ? x : ALPHA_*x; }

__device__ __forceinline__ float wave_sum(float t){
  #pragma unroll
  for (int m = 1; m < 64; m <<= 1) t += __shfl_xor(t, m, 64);
  return t;
}

// ---- detect: are float inputs bf16-packed (flag=1) or f32 (flag=0)? -------
__global__ void detect_kernel(const uint32_t* __restrict__ emb_raw, int* __restrict__ flag){
  if (threadIdx.x == 0 && blockIdx.x == 0){
    int ok = 1;
    for (int i = 0; i < 64; i++){
      uint32_t lo = emb_raw[i] & 0xffffu;
      uint32_t ex = (lo >> 7) & 0xFFu;
      if (!(lo == 0u || (ex >= 64u && ex <= 126u))) ok = 0;
    }
    *flag = ok;
  }
}

// ---- convert: src (bf16-packed or f32 per flag) -> dst bf16 ---------------
__global__ void cvt_kernel(const void* __restrict__ src, ushort_t* __restrict__ dst,
                           int n, const int* __restrict__ flag){
  int i = blockIdx.x*256 + threadIdx.x;
  if (i >= n) return;
  if (*flag){
    dst[i] = ((const ushort_t*)src)[i];
  } else {
    dst[i] = f2bf(((const float*)src)[i]);
  }
}

// ---- sess: masked mean of item embeddings -> f32 (B,D) --------------------
__global__ void sess_kernel(const int* __restrict__ item, const int* __restrict__ mask,
                            const ushort_t* __restrict__ emb, float* __restrict__ sess){
  int b = blockIdx.x, d = threadIdx.x;
  float acc = 0.f, den = 0.f;
  for (int s = 0; s < S_; s++){
    float fm = (float)mask[b*S_ + s];
    int id = item[b*S_ + s];
    acc += fm * bf2f(emb[(size_t)id*D_ + d]);
    den += fm;
  }
  sess[b*D_ + d] = acc / den;
}

// ---- local attention: one 128-thread block per (b,i) ----------------------
__global__ void local_kernel(const int* __restrict__ inputs, const int* __restrict__ adj,
                             const ushort_t* __restrict__ emb, const ushort_t* __restrict__ a_local,
                             ushort_t* __restrict__ hlb){
  int bi = blockIdx.x;               // b*50+i
  int b  = bi / S_;
  int i  = bi - b*S_;
  int t  = threadIdx.x;              // 0..127
  const int* ids = inputs + b*S_;
  __shared__ float es[S_];
  __shared__ float att[S_];
  if (t < S_){
    int kk = adj[(size_t)bi*S_ + t];
    float ev = -9.0e15f;
    if (kk != 0){
      const ushort_t* hi = emb + (size_t)ids[i]*D_;
      const ushort_t* hj = emb + (size_t)ids[t]*D_;
      const ushort_t* al = a_local + (kk-1)*D_;
      float acc = 0.f;
      for (int d = 0; d < D_; d++)
        acc += bf2f(hi[d]) * bf2f(hj[d]) * bf2f(al[d]);
      ev = leaky(acc);
    }
    es[t] = ev;
  }
  __syncthreads();
  if (t == 0){
    float mx = -__builtin_inff();
    for (int j = 0; j < S_; j++) mx = fmaxf(mx, es[j]);
    float s = 0.f;
    for (int j = 0; j < S_; j++){ att[j] = __expf(es[j] - mx); s += att[j]; }
    float inv = 1.f / s;
    for (int j = 0; j < S_; j++) att[j] *= inv;
  }
  __syncthreads();
  float o = 0.f;
  for (int j = 0; j < S_; j++)
    o += att[j] * bf2f(emb[(size_t)ids[j]*D_ + t]);
  hlb[(size_t)bi*D_ + t] = f2bf(o);
}

// ---- fused score: x = sess (*) neigh built in regs, shfl-broadcast --------
// score[m] = sum_e w2[e] * leaky( sum_d x[m,d] * w1[d,e] )  (rows chunk-local)
// MODE0: RPB=600,  neigh = emb[neigh1[row]]
// MODE1: RPB=1200, neigh = emb[adj_all[neigh1[row>>1]*2 + (row&1)]]
// MODE2: RPB=600,  neigh = out1[row]
template<int MODE>
__global__ __launch_bounds__(256) void score_fused(
    const float* __restrict__ sess, const ushort_t* __restrict__ emb,
    const int* __restrict__ neigh1, const int* __restrict__ adj_all,
    const ushort_t* __restrict__ out1,
    const ushort_t* __restrict__ w1, const ushort_t* __restrict__ w2,
    float* __restrict__ score, int NB){
  __shared__ uint32_t w1p[128][64];   // 32 KB: pack w1[d][e] | w1[d][e+64]
  int tid = threadIdx.x;
  for (int i = tid; i < 8192; i += 256){
    int d = i >> 6, e = i & 63;
    w1p[d][e] = (uint32_t)w1[d*128 + e] | ((uint32_t)w1[d*128 + e + 64] << 16);
  }
  __syncthreads();
  int lane = tid & 63, wave = tid >> 6;
  float w2a = bf2f(w2[lane]), w2b = bf2f(w2[lane + 64]);
  const int RPB = (MODE == 1) ? 1200 : 600;
  for (int batch = 0; batch < NB; batch++){
    int mbase = blockIdx.x*(NB*32) + batch*32 + wave*8;
    int b = mbase / RPB;                  // uniform over the 8 rows (8 | RPB)
    float s0 = sess[b*D_ + lane], s1 = sess[b*D_ + lane + 64];
    float xl[8], xh[8];
    #pragma unroll
    for (int r = 0; r < 8; r++){
      int row = mbase + r;
      const ushort_t* src;
      if (MODE == 0)      src = emb  + (size_t)neigh1[row]*D_;
      else if (MODE == 1) src = emb  + (size_t)adj_all[ (size_t)neigh1[row>>1]*2 + (row&1) ]*D_;
      else                src = out1 + (size_t)row*D_;
      xl[r] = s0 * bf2f(src[lane]);
      xh[r] = s1 * bf2f(src[lane + 64]);
    }
    float acc0[8] = {0,0,0,0,0,0,0,0};
    float acc1[8] = {0,0,0,0,0,0,0,0};
    #pragma unroll 8
    for (int dd = 0; dd < 64; dd++){
      uint32_t wA = w1p[dd][lane];        // k=dd:     cols lane | lane+64
      uint32_t wB = w1p[dd + 64][lane];   // k=dd+64:  cols lane | lane+64
      float wA0 = __uint_as_float(wA << 16);
      float wA1 = __uint_as_float(wA & 0xffff0000u);
      float wB0 = __uint_as_float(wB << 16);
      float wB1 = __uint_as_float(wB & 0xffff0000u);
      #pragma unroll
      for (int r = 0; r < 8; r++){
        float x0 = __shfl(xl[r], dd, 64);      // x[dd]
        float x1 = __shfl(xh[r], dd, 64);      // x[dd+64]
        acc0[r] = fmaf(x0, wA0, acc0[r]);
        acc0[r] = fmaf(x1, wB0, acc0[r]);
        acc1[r] = fmaf(x0, wA1, acc1[r]);
        acc1[r] = fmaf(x1, wB1, acc1[r]);
      }
    }
    #pragma unroll
    for (int r = 0; r < 8; r++){
      float t = leaky(acc0[r])*w2a + leaky(acc1[r])*w2b;
      t = wave_sum(t);
      if (lane == 0) score[mbase + r] = t;
    }
  }
}

// ---- fused: softmax(K) + weighted agg (regs) + concat-mm w3 + relu --------
// (rows chunk-local)
// MODE0: K=12, neigh=emb[nbr[row*12+k]],         self=emb[idx[row]]   -> outb
// MODE1: K=2,  neigh=emb[adj_all[nbr[row]*2+k]], self=emb[idx[row]]   -> outb
// MODE2: K=12, neigh=out1[row*12+k],             self=selfsrc[row]    -> outf (f32, +addsrc)
template<int MODE>
__global__ __launch_bounds__(256) void out_fused(
    const float* __restrict__ score, const int* __restrict__ idx,
    const int* __restrict__ nbr, const int* __restrict__ adj_all,
    const ushort_t* __restrict__ emb, const ushort_t* __restrict__ out1,
    const ushort_t* __restrict__ selfsrc,
    const ushort_t* __restrict__ w3, const ushort_t* __restrict__ bias,
    const ushort_t* __restrict__ addsrc,
    ushort_t* __restrict__ outb, float* __restrict__ outf, int NB){
  const int K = (MODE == 1) ? 2 : 12;
  __shared__ uint32_t wp[256][64];   // 64 KB: pack w3[d][e] | w3[d][e+64]
  int tid = threadIdx.x;
  for (int i = tid; i < 16384; i += 256){
    int d = i >> 6, e = i & 63;
    wp[d][e] = (uint32_t)w3[d*128 + e] | ((uint32_t)w3[d*128 + e + 64] << 16);
  }
  __syncthreads();
  int lane = tid & 63, wave = tid >> 6;
  float bi0 = bf2f(bias[lane]), bi1 = bf2f(bias[lane + 64]);
  for (int batch = 0; batch < NB; batch++){
    int mbase = blockIdx.x*(NB*32) + batch*32 + wave*8;
    // per-row softmax + register agg: lane holds d = 2*lane, 2*lane+1
    float agg0[8], agg1[8];
    const uint32_t* sp[8];
    #pragma unroll
    for (int r = 0; r < 8; r++){
      int row = __builtin_amdgcn_readfirstlane(mbase + r);
      int srow = (MODE == 2) ? row : idx[row];
      sp[r] = (const uint32_t*)selfsrc + (size_t)srow * 64;
      const float* sc = score + (size_t)row * K;
      float a[K]; float mx = -__builtin_inff();
      #pragma unroll
      for (int k = 0; k < K; k++) mx = fmaxf(mx, sc[k]);
      float ssum = 0.f;
      #pragma unroll
      for (int k = 0; k < K; k++){ a[k] = __expf(sc[k] - mx); ssum += a[k]; }
      float inv = 1.f / ssum;
      float g0 = 0.f, g1 = 0.f;
      #pragma unroll
      for (int k = 0; k < K; k++){
        const uint32_t* npd;
        if (MODE == 0)      npd = (const uint32_t*)emb  + (size_t)nbr[row*12 + k] * 64;
        else if (MODE == 1) npd = (const uint32_t*)emb  + (size_t)adj_all[(size_t)nbr[row]*2 + k] * 64;
        else                npd = (const uint32_t*)out1 + (size_t)(row*12 + k) * 64;
        uint32_t p = npd[lane];
        g0 = fmaf(a[k], __uint_as_float(p << 16),         g0);
        g1 = fmaf(a[k], __uint_as_float(p & 0xffff0000u), g1);
      }
      agg0[r] = g0 * inv;
      agg1[r] = g1 * inv;
    }
    // mm over concat(self, agg)
    float acc0[8] = {0,0,0,0,0,0,0,0};
    float acc1[8] = {0,0,0,0,0,0,0,0};
    #pragma unroll 4
    for (int dd = 0; dd < 64; dd++){
      uint32_t wT0 = wp[2*dd][lane];         // w3 row 2dd
      uint32_t wT1 = wp[2*dd + 1][lane];     // w3 row 2dd+1
      uint32_t wB0 = wp[128 + 2*dd][lane];   // w3 row 128+2dd
      uint32_t wB1 = wp[129 + 2*dd][lane];   // w3 row 128+2dd+1
      float wT0l = __uint_as_float(wT0 << 16), wT0h = __uint_as_float(wT0 & 0xffff0000u);
      float wT1l = __uint_as_float(wT1 << 16), wT1h = __uint_as_float(wT1 & 0xffff0000u);
      float wB0l = __uint_as_float(wB0 << 16), wB0h = __uint_as_float(wB0 & 0xffff0000u);
      float wB1l = __uint_as_float(wB1 << 16), wB1h = __uint_as_float(wB1 & 0xffff0000u);
      #pragma unroll
      for (int r = 0; r < 8; r++){
        uint32_t zs = sp[r][dd];                 // self[2dd], self[2dd+1] (uniform addr)
        float z0 = __uint_as_float(zs << 16);
        float z1 = __uint_as_float(zs & 0xffff0000u);
        float z2 = __shfl(agg0[r], dd, 64);      // agg[2dd]
        float z3 = __shfl(agg1[r], dd, 64);      // agg[2dd+1]
        acc0[r] = fmaf(z0, wT0l, acc0[r]);
        acc0[r] = fmaf(z1, wT1l, acc0[r]);
        acc0[r] = fmaf(z2, wB0l, acc0[r]);
        acc0[r] = fmaf(z3, wB1l, acc0[r]);
        acc1[r] = fmaf(z0, wT0h, acc1[r]);
        acc1[r] = fmaf(z1, wT1h, acc1[r]);
        acc1[r] = fmaf(z2, wB0h, acc1[r]);
        acc1[r] = fmaf(z3, wB1h, acc1[r]);
      }
    }
    #pragma unroll
    for (int r = 0; r < 8; r++){
      float v0 = fmaxf(acc0[r] + bi0, 0.f);
      float v1 = fmaxf(acc1[r] + bi1, 0.f);
      if (MODE == 2){
        v0 += bf2f(addsrc[(size_t)(mbase + r)*D_ + lane]);
        v1 += bf2f(addsrc[(size_t)(mbase + r)*D_ + lane + 64]);
        outf[(size_t)(mbase + r)*D_ + lane]      = v0;   // FINAL: f32 storage
        outf[(size_t)(mbase + r)*D_ + lane + 64] = v1;
      } else {
        outb[(size_t)(mbase + r)*D_ + lane]      = f2bf(v0);
        outb[(size_t)(mbase + r)*D_ + lane + 64] = f2bf(v1);
      }
    }
  }
}

extern "C" void kernel_launch(void* const* d_in, const int* in_sizes, int n_in,
                              void* d_out, int out_size, void* d_ws, size_t ws_size,
                              hipStream_t stream) {
  const int* inputs    = (const int*)d_in[0];
  const int* adj       = (const int*)d_in[1];
  const int* mask_item = (const int*)d_in[2];
  const int* item      = (const int*)d_in[3];
  const int* first_adj = (const int*)d_in[4];    // neigh1 (B,600)
  const int* adj_all   = (const int*)d_in[5];    // (50000,2)

  // ---- ws layout ----
  char* ws = (char*)d_ws;
  size_t o = 0;
  int*      flag   = (int*)(ws + o);      o += 64;
  ushort_t* emb_b  = (ushort_t*)(ws + o); o += 12800000;  // 50000*128 bf16
  ushort_t* alocb  = (ushort_t*)(ws + o); o += 1024;      // 4*128
  ushort_t* gw1b   = (ushort_t*)(ws + o); o += 65536;     // 2*128*128
  ushort_t* gw2b   = (ushort_t*)(ws + o); o += 512;       // 2*128
  ushort_t* gw3b   = (ushort_t*)(ws + o); o += 131072;    // 2*256*128
  ushort_t* gbb    = (ushort_t*)(ws + o); o += 512;       // 2*128
  float*    sess_f = (float*)(ws + o);    o += 65536;     // 128*128 f32
  ushort_t* hlb    = (ushort_t*)(ws + o); o += 1638400;   // 6400*128 bf16
  size_t fixed = o;
  // variable: out1c CHB*153600 + o0c CHB*12800 + score CHB*4800 = CHB*171200
  int CHB = 16;
  if      (ws_size >= fixed + (size_t)128*171200) CHB = 128;
  else if (ws_size >= fixed + (size_t)64 *171200) CHB = 64;
  else if (ws_size >= fixed + (size_t)32 *171200) CHB = 32;
  ushort_t* out1c = (ushort_t*)(ws + o);  o += (size_t)CHB*153600;
  ushort_t* o0c   = (ushort_t*)(ws + o);  o += (size_t)CHB*12800;
  float*    score = (float*)(ws + o);

  float* outp = (float*)d_out;   // output is f32 storage

  // ---- dtype normalize ----
  detect_kernel<<<1, 64, 0, stream>>>((const uint32_t*)d_in[6], flag);
  cvt_kernel<<<(6400000+255)/256, 256, 0, stream>>>(d_in[6],  emb_b, 6400000, flag);
  cvt_kernel<<<(512+255)/256,     256, 0, stream>>>(d_in[7],  alocb, 512,     flag);
  cvt_kernel<<<(32768+255)/256,   256, 0, stream>>>(d_in[8],  gw1b,  32768,   flag);
  cvt_kernel<<<(256+255)/256,     256, 0, stream>>>(d_in[9],  gw2b,  256,     flag);
  cvt_kernel<<<(65536+255)/256,   256, 0, stream>>>(d_in[10], gw3b,  65536,   flag);
  cvt_kernel<<<(256+255)/256,     256, 0, stream>>>(d_in[11], gbb,   256,     flag);

  sess_kernel <<<B_, 128, 0, stream>>>(item, mask_item, emb_b, sess_f);
  local_kernel<<<B_*S_, 128, 0, stream>>>(inputs, adj, emb_b, alocb, hlb);

  int nchunk = B_ / CHB;
  for (int c = 0; c < nchunk; c++){
    int b0 = c * CHB;
    const float* sessc = sess_f + (size_t)b0 * D_;
    const int*   fadj  = first_adj + (size_t)b0 * 600;
    ushort_t*    hlc   = hlb  + (size_t)b0 * 50 * D_;
    float*       outc  = outp + (size_t)b0 * 50 * D_;

    // call A: hop-0 weights; scores CHB*600; out CHB*50 -> o0c (bf16)
    score_fused<0><<<CHB*600/64, 256, 0, stream>>>(sessc, emb_b, fadj, adj_all, out1c,
                                                   gw1b, gw2b, score, 2);
    out_fused<0><<<CHB*50/32, 256, 0, stream>>>(score, inputs + b0*50, fadj, adj_all,
                                                emb_b, out1c, emb_b, gw3b, gbb,
                                                nullptr, o0c, nullptr, 1);
    // call B: hop-0 weights; scores CHB*1200; out CHB*600 -> out1c (bf16)
    score_fused<1><<<CHB*1200/64, 256, 0, stream>>>(sessc, emb_b, fadj, adj_all, out1c,
                                                    gw1b, gw2b, score, 2);
    out_fused<1><<<CHB*600/64, 256, 0, stream>>>(score, fadj, fadj, adj_all,
                                                 emb_b, out1c, emb_b, gw3b, gbb,
                                                 nullptr, out1c, nullptr, 2);
    // call C: hop-1 weights; scores CHB*600; out CHB*50 -> d_out (f32, +h_local)
    score_fused<2><<<CHB*600/64, 256, 0, stream>>>(sessc, emb_b, fadj, adj_all, out1c,
                                                   gw1b + 16384, gw2b + 128, score, 2);
    out_fused<2><<<CHB*50/32, 256, 0, stream>>>(score, nullptr, fadj, adj_all,
                                                emb_b, out1c, o0c, gw3b + 32768, gbb + 128,
                                                hlc, nullptr, outc, 1);
  }
}

// Round 9
// 434.120 us; speedup vs baseline: 2.9776x; 1.9951x over previous
//
#include <hip/hip_runtime.h>
#include <stdint.h>

typedef unsigned short ushort_t;
typedef __attribute__((ext_vector_type(8))) short bf16x8;   // 4 VGPRs, 8 bf16
typedef __attribute__((ext_vector_type(4))) float f32x4;    // MFMA C/D

#define B_   128
#define S_   50
#define D_   128
#define ALPHA_ 0.2f

__device__ __forceinline__ float bf2f(ushort_t u){
  return __uint_as_float(((uint32_t)u) << 16);
}
__device__ __forceinline__ ushort_t f2bf(float f){
  uint32_t x = __float_as_uint(f);
  x = (x + 0x7fffu + ((x >> 16) & 1u)) >> 16;
  return (ushort_t)x;
}
__device__ __forceinline__ float leaky(float x){ return x >= 0.f ? x : ALPHA_*x; }

__device__ __forceinline__ float wave_sum(float t){
  #pragma unroll
  for (int m = 1; m < 64; m <<= 1) t += __shfl_xor(t, m, 64);
  return t;
}

// ---- detect: are float inputs bf16-packed (flag=1) or f32 (flag=0)? -------
__global__ void detect_kernel(const uint32_t* __restrict__ emb_raw, int* __restrict__ flag){
  if (threadIdx.x == 0 && blockIdx.x == 0){
    int ok = 1;
    for (int i = 0; i < 64; i++){
      uint32_t lo = emb_raw[i] & 0xffffu;
      uint32_t ex = (lo >> 7) & 0xFFu;
      if (!(lo == 0u || (ex >= 64u && ex <= 126u))) ok = 0;
    }
    *flag = ok;
  }
}

// ---- convert: src (bf16-packed or f32 per flag) -> dst bf16 ---------------
__global__ void cvt_kernel(const void* __restrict__ src, ushort_t* __restrict__ dst,
                           int n, const int* __restrict__ flag){
  int i = blockIdx.x*256 + threadIdx.x;
  if (i >= n) return;
  if (*flag){
    dst[i] = ((const ushort_t*)src)[i];
  } else {
    dst[i] = f2bf(((const float*)src)[i]);
  }
}

// ---- sess: masked mean of item embeddings -> f32 + bf16 (B,D) -------------
__global__ void sess_kernel(const int* __restrict__ item, const int* __restrict__ mask,
                            const ushort_t* __restrict__ emb, float* __restrict__ sess,
                            ushort_t* __restrict__ sessb){
  int b = blockIdx.x, d = threadIdx.x;
  float acc = 0.f, den = 0.f;
  for (int s = 0; s < S_; s++){
    float fm = (float)mask[b*S_ + s];
    int id = item[b*S_ + s];
    acc += fm * bf2f(emb[(size_t)id*D_ + d]);
    den += fm;
  }
  float v = acc / den;
  sess[b*D_ + d]  = v;
  sessb[b*D_ + d] = f2bf(v);
}

// ---- local attention: one 128-thread block per (b,i) ----------------------
__global__ void local_kernel(const int* __restrict__ inputs, const int* __restrict__ adj,
                             const ushort_t* __restrict__ emb, const ushort_t* __restrict__ a_local,
                             ushort_t* __restrict__ hlb){
  int bi = blockIdx.x;               // b*50+i
  int b  = bi / S_;
  int i  = bi - b*S_;
  int t  = threadIdx.x;              // 0..127
  const int* ids = inputs + b*S_;
  __shared__ float es[S_];
  __shared__ float att[S_];
  if (t < S_){
    int kk = adj[(size_t)bi*S_ + t];
    float ev = -9.0e15f;
    if (kk != 0){
      const ushort_t* hi = emb + (size_t)ids[i]*D_;
      const ushort_t* hj = emb + (size_t)ids[t]*D_;
      const ushort_t* al = a_local + (kk-1)*D_;
      float acc = 0.f;
      for (int d = 0; d < D_; d++)
        acc += bf2f(hi[d]) * bf2f(hj[d]) * bf2f(al[d]);
      ev = leaky(acc);
    }
    es[t] = ev;
  }
  __syncthreads();
  if (t == 0){
    float mx = -__builtin_inff();
    for (int j = 0; j < S_; j++) mx = fmaxf(mx, es[j]);
    float s = 0.f;
    for (int j = 0; j < S_; j++){ att[j] = __expf(es[j] - mx); s += att[j]; }
    float inv = 1.f / s;
    for (int j = 0; j < S_; j++) att[j] *= inv;
  }
  __syncthreads();
  float o = 0.f;
  for (int j = 0; j < S_; j++)
    o += att[j] * bf2f(emb[(size_t)ids[j]*D_ + t]);
  hlb[(size_t)bi*D_ + t] = f2bf(o);
}

// ---- MFMA score: score[m] = sum_e w2[e]*leaky( (sess(*)neigh @ w1)[m][e] ) -
// 16x16x32 bf16 MFMA. Per wave: 16 rows. Block 256 thr = 4 waves; 2 iters
// => 128 rows/block. Fragment layouts (guide-verified):
//   A[m=lane&15][k=(lane>>4)*8+j], B[k=(lane>>4)*8+j][n=lane&15],
//   D col=lane&15, row=(lane>>4)*4+reg.
// MODE0: RPB=600,  neigh = emb[neigh1[row]]
// MODE1: RPB=1200, neigh = emb[adj_all[neigh1[row>>1]*2 + (row&1)]]
// MODE2: RPB=600,  neigh = out1[row]
template<int MODE>
__global__ __launch_bounds__(256) void score_mfma(
    const ushort_t* __restrict__ sessb, const ushort_t* __restrict__ emb,
    const int* __restrict__ neigh1, const int* __restrict__ adj_all,
    const ushort_t* __restrict__ out1,
    const ushort_t* __restrict__ w1, const ushort_t* __restrict__ w2,
    float* __restrict__ score){
  __shared__ uint4 bfrag[2048];      // 32 KB: [kt][t][lane] -> 8 bf16 of w1
  int tid = threadIdx.x;
  for (int idx = tid; idx < 2048; idx += 256){
    int kt = idx >> 9, rem = idx & 511, t = rem >> 6, ln = rem & 63;
    int q = ln >> 4, c = ln & 15;
    union { ushort_t u[8]; uint4 q4; } e;
    #pragma unroll
    for (int j = 0; j < 8; j++)
      e.u[j] = w1[(32*kt + q*8 + j)*128 + 16*t + c];
    bfrag[idx] = e.q4;
  }
  __syncthreads();
  int lane = tid & 63, wave = tid >> 6;
  int m = lane & 15, q = lane >> 4;
  const int RPB = (MODE == 1) ? 1200 : 600;
  float w2v[8];
  #pragma unroll
  for (int t = 0; t < 8; t++) w2v[t] = bf2f(w2[16*t + m]);

  for (int it = 0; it < 2; it++){
    int row_base = blockIdx.x*128 + it*64 + wave*16;
    int row = row_base + m;
    const ushort_t* nrow;
    if (MODE == 0)      nrow = emb  + (size_t)neigh1[row]*D_;
    else if (MODE == 1) nrow = emb  + (size_t)adj_all[(size_t)neigh1[row>>1]*2 + (row&1)]*D_;
    else                nrow = out1 + (size_t)row*D_;
    int b = row / RPB;
    const ushort_t* srow = sessb + (size_t)b*D_;

    f32x4 acc[8];
    #pragma unroll
    for (int t = 0; t < 8; t++) acc[t] = (f32x4){0.f,0.f,0.f,0.f};

    #pragma unroll
    for (int kt = 0; kt < 4; kt++){
      // A-frag: x[m][32kt + q*8 + j] = sess[b][..] * neigh[m][..], bf16
      uint4 nv = *(const uint4*)(nrow + kt*32 + q*8);
      uint4 sv = *(const uint4*)(srow + kt*32 + q*8);
      const uint32_t* np = (const uint32_t*)&nv;
      const uint32_t* sp = (const uint32_t*)&sv;
      union { ushort_t u[8]; bf16x8 v; } afr;
      #pragma unroll
      for (int p = 0; p < 4; p++){
        uint32_t n2 = np[p], s2 = sp[p];
        float a0 = __uint_as_float(n2 << 16)          * __uint_as_float(s2 << 16);
        float a1 = __uint_as_float(n2 & 0xffff0000u)  * __uint_as_float(s2 & 0xffff0000u);
        afr.u[2*p]   = f2bf(a0);
        afr.u[2*p+1] = f2bf(a1);
      }
      #pragma unroll
      for (int t = 0; t < 8; t++){
        union { uint4 q4; bf16x8 v; } bfr;
        bfr.q4 = bfrag[(kt*8 + t)*64 + lane];
        acc[t] = __builtin_amdgcn_mfma_f32_16x16x32_bf16(afr.v, bfr.v, acc[t], 0, 0, 0);
      }
    }
    // epilogue: leaky, *w2, sum over e (8 tiles x 16 cols)
    #pragma unroll
    for (int r = 0; r < 4; r++){
      float s = 0.f;
      #pragma unroll
      for (int t = 0; t < 8; t++) s += leaky(acc[t][r]) * w2v[t];
      s += __shfl_xor(s, 1, 64);
      s += __shfl_xor(s, 2, 64);
      s += __shfl_xor(s, 4, 64);
      s += __shfl_xor(s, 8, 64);
      if (m == 0) score[row_base + q*4 + r] = s;
    }
  }
}

// ---- fused: softmax(K) + weighted agg (regs) + concat-mm w3 + relu --------
// MODE0: K=12, neigh=emb[nbr[row*12+k]],         self=emb[idx[row]]   -> outb
// MODE1: K=2,  neigh=emb[adj_all[nbr[row]*2+k]], self=emb[idx[row]]   -> outb
// MODE2: K=12, neigh=out1[row*12+k],             self=selfsrc[row]    -> outf (f32, +addsrc)
template<int MODE>
__global__ __launch_bounds__(256) void out_fused(
    const float* __restrict__ score, const int* __restrict__ idx,
    const int* __restrict__ nbr, const int* __restrict__ adj_all,
    const ushort_t* __restrict__ emb, const ushort_t* __restrict__ out1,
    const ushort_t* __restrict__ selfsrc,
    const ushort_t* __restrict__ w3, const ushort_t* __restrict__ bias,
    const ushort_t* __restrict__ addsrc,
    ushort_t* __restrict__ outb, float* __restrict__ outf, int NB){
  const int K = (MODE == 1) ? 2 : 12;
  __shared__ uint32_t wp[256][64];   // 64 KB: pack w3[d][e] | w3[d][e+64]
  int tid = threadIdx.x;
  for (int i = tid; i < 16384; i += 256){
    int d = i >> 6, e = i & 63;
    wp[d][e] = (uint32_t)w3[d*128 + e] | ((uint32_t)w3[d*128 + e + 64] << 16);
  }
  __syncthreads();
  int lane = tid & 63, wave = tid >> 6;
  float bi0 = bf2f(bias[lane]), bi1 = bf2f(bias[lane + 64]);
  for (int batch = 0; batch < NB; batch++){
    int mbase = blockIdx.x*(NB*32) + batch*32 + wave*8;
    float agg0[8], agg1[8];
    const uint32_t* sp[8];
    #pragma unroll
    for (int r = 0; r < 8; r++){
      int row = __builtin_amdgcn_readfirstlane(mbase + r);
      int srow = (MODE == 2) ? row : idx[row];
      sp[r] = (const uint32_t*)selfsrc + (size_t)srow * 64;
      const float* sc = score + (size_t)row * K;
      float a[K]; float mx = -__builtin_inff();
      #pragma unroll
      for (int k = 0; k < K; k++) mx = fmaxf(mx, sc[k]);
      float ssum = 0.f;
      #pragma unroll
      for (int k = 0; k < K; k++){ a[k] = __expf(sc[k] - mx); ssum += a[k]; }
      float inv = 1.f / ssum;
      float g0 = 0.f, g1 = 0.f;
      #pragma unroll
      for (int k = 0; k < K; k++){
        const uint32_t* npd;
        if (MODE == 0)      npd = (const uint32_t*)emb  + (size_t)nbr[row*12 + k] * 64;
        else if (MODE == 1) npd = (const uint32_t*)emb  + (size_t)adj_all[(size_t)nbr[row]*2 + k] * 64;
        else                npd = (const uint32_t*)out1 + (size_t)(row*12 + k) * 64;
        uint32_t p = npd[lane];
        g0 = fmaf(a[k], __uint_as_float(p << 16),         g0);
        g1 = fmaf(a[k], __uint_as_float(p & 0xffff0000u), g1);
      }
      agg0[r] = g0 * inv;
      agg1[r] = g1 * inv;
    }
    float acc0[8] = {0,0,0,0,0,0,0,0};
    float acc1[8] = {0,0,0,0,0,0,0,0};
    #pragma unroll 4
    for (int dd = 0; dd < 64; dd++){
      uint32_t wT0 = wp[2*dd][lane];
      uint32_t wT1 = wp[2*dd + 1][lane];
      uint32_t wB0 = wp[128 + 2*dd][lane];
      uint32_t wB1 = wp[129 + 2*dd][lane];
      float wT0l = __uint_as_float(wT0 << 16), wT0h = __uint_as_float(wT0 & 0xffff0000u);
      float wT1l = __uint_as_float(wT1 << 16), wT1h = __uint_as_float(wT1 & 0xffff0000u);
      float wB0l = __uint_as_float(wB0 << 16), wB0h = __uint_as_float(wB0 & 0xffff0000u);
      float wB1l = __uint_as_float(wB1 << 16), wB1h = __uint_as_float(wB1 & 0xffff0000u);
      #pragma unroll
      for (int r = 0; r < 8; r++){
        uint32_t zs = sp[r][dd];
        float z0 = __uint_as_float(zs << 16);
        float z1 = __uint_as_float(zs & 0xffff0000u);
        float z2 = __shfl(agg0[r], dd, 64);
        float z3 = __shfl(agg1[r], dd, 64);
        acc0[r] = fmaf(z0, wT0l, acc0[r]);
        acc0[r] = fmaf(z1, wT1l, acc0[r]);
        acc0[r] = fmaf(z2, wB0l, acc0[r]);
        acc0[r] = fmaf(z3, wB1l, acc0[r]);
        acc1[r] = fmaf(z0, wT0h, acc1[r]);
        acc1[r] = fmaf(z1, wT1h, acc1[r]);
        acc1[r] = fmaf(z2, wB0h, acc1[r]);
        acc1[r] = fmaf(z3, wB1h, acc1[r]);
      }
    }
    #pragma unroll
    for (int r = 0; r < 8; r++){
      float v0 = fmaxf(acc0[r] + bi0, 0.f);
      float v1 = fmaxf(acc1[r] + bi1, 0.f);
      if (MODE == 2){
        v0 += bf2f(addsrc[(size_t)(mbase + r)*D_ + lane]);
        v1 += bf2f(addsrc[(size_t)(mbase + r)*D_ + lane + 64]);
        outf[(size_t)(mbase + r)*D_ + lane]      = v0;   // FINAL: f32 storage
        outf[(size_t)(mbase + r)*D_ + lane + 64] = v1;
      } else {
        outb[(size_t)(mbase + r)*D_ + lane]      = f2bf(v0);
        outb[(size_t)(mbase + r)*D_ + lane + 64] = f2bf(v1);
      }
    }
  }
}

extern "C" void kernel_launch(void* const* d_in, const int* in_sizes, int n_in,
                              void* d_out, int out_size, void* d_ws, size_t ws_size,
                              hipStream_t stream) {
  const int* inputs    = (const int*)d_in[0];
  const int* adj       = (const int*)d_in[1];
  const int* mask_item = (const int*)d_in[2];
  const int* item      = (const int*)d_in[3];
  const int* first_adj = (const int*)d_in[4];    // neigh1 (B,600)
  const int* adj_all   = (const int*)d_in[5];    // (50000,2)

  // ---- ws layout ----
  char* ws = (char*)d_ws;
  size_t o = 0;
  int*      flag   = (int*)(ws + o);      o += 64;
  ushort_t* emb_b  = (ushort_t*)(ws + o); o += 12800000;  // 50000*128 bf16
  ushort_t* alocb  = (ushort_t*)(ws + o); o += 1024;      // 4*128
  ushort_t* gw1b   = (ushort_t*)(ws + o); o += 65536;     // 2*128*128
  ushort_t* gw2b   = (ushort_t*)(ws + o); o += 512;       // 2*128
  ushort_t* gw3b   = (ushort_t*)(ws + o); o += 131072;    // 2*256*128
  ushort_t* gbb    = (ushort_t*)(ws + o); o += 512;       // 2*128
  float*    sess_f = (float*)(ws + o);    o += 65536;     // 128*128 f32
  ushort_t* sessb  = (ushort_t*)(ws + o); o += 32768;     // 128*128 bf16
  ushort_t* hlb    = (ushort_t*)(ws + o); o += 1638400;   // 6400*128 bf16
  size_t fixed = o;
  // variable: out1c CHB*153600 + o0c CHB*12800 + score CHB*4800 = CHB*171200
  int CHB = 16;
  if      (ws_size >= fixed + (size_t)128*171200) CHB = 128;
  else if (ws_size >= fixed + (size_t)64 *171200) CHB = 64;
  else if (ws_size >= fixed + (size_t)32 *171200) CHB = 32;
  ushort_t* out1c = (ushort_t*)(ws + o);  o += (size_t)CHB*153600;
  ushort_t* o0c   = (ushort_t*)(ws + o);  o += (size_t)CHB*12800;
  float*    score = (float*)(ws + o);

  float* outp = (float*)d_out;   // output is f32 storage

  // ---- dtype normalize ----
  detect_kernel<<<1, 64, 0, stream>>>((const uint32_t*)d_in[6], flag);
  cvt_kernel<<<(6400000+255)/256, 256, 0, stream>>>(d_in[6],  emb_b, 6400000, flag);
  cvt_kernel<<<(512+255)/256,     256, 0, stream>>>(d_in[7],  alocb, 512,     flag);
  cvt_kernel<<<(32768+255)/256,   256, 0, stream>>>(d_in[8],  gw1b,  32768,   flag);
  cvt_kernel<<<(256+255)/256,     256, 0, stream>>>(d_in[9],  gw2b,  256,     flag);
  cvt_kernel<<<(65536+255)/256,   256, 0, stream>>>(d_in[10], gw3b,  65536,   flag);
  cvt_kernel<<<(256+255)/256,     256, 0, stream>>>(d_in[11], gbb,   256,     flag);

  sess_kernel <<<B_, 128, 0, stream>>>(item, mask_item, emb_b, sess_f, sessb);
  local_kernel<<<B_*S_, 128, 0, stream>>>(inputs, adj, emb_b, alocb, hlb);

  int nchunk = B_ / CHB;
  for (int c = 0; c < nchunk; c++){
    int b0 = c * CHB;
    const int* fadj  = first_adj + (size_t)b0 * 600;
    const ushort_t* sbc = sessb + (size_t)b0 * D_;
    ushort_t*  hlc   = hlb  + (size_t)b0 * 50 * D_;
    float*     outc  = outp + (size_t)b0 * 50 * D_;

    // call A: hop-0 weights; scores CHB*600; out CHB*50 -> o0c (bf16)
    score_mfma<0><<<CHB*600/128, 256, 0, stream>>>(sbc, emb_b, fadj, adj_all, out1c,
                                                   gw1b, gw2b, score);
    out_fused<0><<<CHB*50/32, 256, 0, stream>>>(score, inputs + b0*50, fadj, adj_all,
                                                emb_b, out1c, emb_b, gw3b, gbb,
                                                nullptr, o0c, nullptr, 1);
    // call B: hop-0 weights; scores CHB*1200; out CHB*600 -> out1c (bf16)
    score_mfma<1><<<CHB*1200/128, 256, 0, stream>>>(sbc, emb_b, fadj, adj_all, out1c,
                                                    gw1b, gw2b, score);
    out_fused<1><<<CHB*600/64, 256, 0, stream>>>(score, fadj, fadj, adj_all,
                                                 emb_b, out1c, emb_b, gw3b, gbb,
                                                 nullptr, out1c, nullptr, 2);
    // call C: hop-1 weights; scores CHB*600; out CHB*50 -> d_out (f32, +h_local)
    score_mfma<2><<<CHB*600/128, 256, 0, stream>>>(sbc, emb_b, fadj, adj_all, out1c,
                                                   gw1b + 16384, gw2b + 128, score);
    out_fused<2><<<CHB*50/32, 256, 0, stream>>>(score, nullptr, fadj, adj_all,
                                                emb_b, out1c, o0c, gw3b + 32768, gbb + 128,
                                                hlc, nullptr, outc, 1);
  }
}

// Round 10
// 269.199 us; speedup vs baseline: 4.8017x; 1.6126x over previous
//
#include <hip/hip_runtime.h>
#include <stdint.h>

typedef unsigned short ushort_t;
typedef __attribute__((ext_vector_type(8))) short bf16x8;   // 4 VGPRs, 8 bf16
typedef __attribute__((ext_vector_type(4))) float f32x4;    // MFMA C/D

#define B_   128
#define S_   50
#define D_   128
#define ALPHA_ 0.2f

__device__ __forceinline__ float bf2f(ushort_t u){
  return __uint_as_float(((uint32_t)u) << 16);
}
__device__ __forceinline__ ushort_t f2bf(float f){
  uint32_t x = __float_as_uint(f);
  x = (x + 0x7fffu + ((x >> 16) & 1u)) >> 16;
  return (ushort_t)x;
}
__device__ __forceinline__ float leaky(float x){ return x >= 0.f ? x : ALPHA_*x; }

// ---- detect: are float inputs bf16-packed (flag=1) or f32 (flag=0)? -------
__global__ void detect_kernel(const uint32_t* __restrict__ emb_raw, int* __restrict__ flag){
  if (threadIdx.x == 0 && blockIdx.x == 0){
    int ok = 1;
    for (int i = 0; i < 64; i++){
      uint32_t lo = emb_raw[i] & 0xffffu;
      uint32_t ex = (lo >> 7) & 0xFFu;
      if (!(lo == 0u || (ex >= 64u && ex <= 126u))) ok = 0;
    }
    *flag = ok;
  }
}

// ---- convert: src (bf16-packed or f32 per flag) -> dst bf16 ---------------
__global__ void cvt_kernel(const void* __restrict__ src, ushort_t* __restrict__ dst,
                           int n, const int* __restrict__ flag){
  int i = blockIdx.x*256 + threadIdx.x;
  if (i >= n) return;
  if (*flag){
    dst[i] = ((const ushort_t*)src)[i];
  } else {
    dst[i] = f2bf(((const float*)src)[i]);
  }
}

// ---- sess: masked mean of item embeddings -> f32 + bf16 (B,D) -------------
__global__ void sess_kernel(const int* __restrict__ item, const int* __restrict__ mask,
                            const ushort_t* __restrict__ emb, float* __restrict__ sess,
                            ushort_t* __restrict__ sessb){
  int b = blockIdx.x, d = threadIdx.x;
  float acc = 0.f, den = 0.f;
  for (int s = 0; s < S_; s++){
    float fm = (float)mask[b*S_ + s];
    int id = item[b*S_ + s];
    acc += fm * bf2f(emb[(size_t)id*D_ + d]);
    den += fm;
  }
  float v = acc / den;
  sess[b*D_ + d]  = v;
  sessb[b*D_ + d] = f2bf(v);
}

// ---- local attention: one 128-thread block per (b,i) ----------------------
__global__ void local_kernel(const int* __restrict__ inputs, const int* __restrict__ adj,
                             const ushort_t* __restrict__ emb, const ushort_t* __restrict__ a_local,
                             ushort_t* __restrict__ hlb){
  int bi = blockIdx.x;               // b*50+i
  int b  = bi / S_;
  int i  = bi - b*S_;
  int t  = threadIdx.x;              // 0..127
  const int* ids = inputs + b*S_;
  __shared__ float es[S_];
  __shared__ float att[S_];
  if (t < S_){
    int kk = adj[(size_t)bi*S_ + t];
    float ev = -9.0e15f;
    if (kk != 0){
      const ushort_t* hi = emb + (size_t)ids[i]*D_;
      const ushort_t* hj = emb + (size_t)ids[t]*D_;
      const ushort_t* al = a_local + (kk-1)*D_;
      float acc = 0.f;
      for (int d = 0; d < D_; d++)
        acc += bf2f(hi[d]) * bf2f(hj[d]) * bf2f(al[d]);
      ev = leaky(acc);
    }
    es[t] = ev;
  }
  __syncthreads();
  if (t == 0){
    float mx = -__builtin_inff();
    for (int j = 0; j < S_; j++) mx = fmaxf(mx, es[j]);
    float s = 0.f;
    for (int j = 0; j < S_; j++){ att[j] = __expf(es[j] - mx); s += att[j]; }
    float inv = 1.f / s;
    for (int j = 0; j < S_; j++) att[j] *= inv;
  }
  __syncthreads();
  float o = 0.f;
  for (int j = 0; j < S_; j++)
    o += att[j] * bf2f(emb[(size_t)ids[j]*D_ + t]);
  hlb[(size_t)bi*D_ + t] = f2bf(o);
}

// ---- MFMA score: score[m] = sum_e w2[e]*leaky( (sess(*)neigh @ w1)[m][e] ) -
// 16x16x32 bf16 MFMA; layouts as validated in round 9.
// MODE0: RPB=600,  neigh = emb[neigh1[row]]
// MODE1: RPB=1200, neigh = emb[adj_all[neigh1[row>>1]*2 + (row&1)]]
// MODE2: RPB=600,  neigh = out1[row]
template<int MODE>
__global__ __launch_bounds__(256) void score_mfma(
    const ushort_t* __restrict__ sessb, const ushort_t* __restrict__ emb,
    const int* __restrict__ neigh1, const int* __restrict__ adj_all,
    const ushort_t* __restrict__ out1,
    const ushort_t* __restrict__ w1, const ushort_t* __restrict__ w2,
    float* __restrict__ score){
  __shared__ uint4 bfrag[2048];      // 32 KB: [kt][t][lane] -> 8 bf16 of w1
  int tid = threadIdx.x;
  for (int idx = tid; idx < 2048; idx += 256){
    int kt = idx >> 9, rem = idx & 511, t = rem >> 6, ln = rem & 63;
    int q = ln >> 4, c = ln & 15;
    union { ushort_t u[8]; uint4 q4; } e;
    #pragma unroll
    for (int j = 0; j < 8; j++)
      e.u[j] = w1[(32*kt + q*8 + j)*128 + 16*t + c];
    bfrag[idx] = e.q4;
  }
  __syncthreads();
  int lane = tid & 63, wave = tid >> 6;
  int m = lane & 15, q = lane >> 4;
  const int RPB = (MODE == 1) ? 1200 : 600;
  float w2v[8];
  #pragma unroll
  for (int t = 0; t < 8; t++) w2v[t] = bf2f(w2[16*t + m]);

  for (int it = 0; it < 2; it++){
    int row_base = blockIdx.x*128 + it*64 + wave*16;
    int row = row_base + m;
    const ushort_t* nrow;
    if (MODE == 0)      nrow = emb  + (size_t)neigh1[row]*D_;
    else if (MODE == 1) nrow = emb  + (size_t)adj_all[(size_t)neigh1[row>>1]*2 + (row&1)]*D_;
    else                nrow = out1 + (size_t)row*D_;
    int b = row / RPB;
    const ushort_t* srow = sessb + (size_t)b*D_;

    f32x4 acc[8];
    #pragma unroll
    for (int t = 0; t < 8; t++) acc[t] = (f32x4){0.f,0.f,0.f,0.f};

    #pragma unroll
    for (int kt = 0; kt < 4; kt++){
      uint4 nv = *(const uint4*)(nrow + kt*32 + q*8);
      uint4 sv = *(const uint4*)(srow + kt*32 + q*8);
      const uint32_t* np = (const uint32_t*)&nv;
      const uint32_t* sp = (const uint32_t*)&sv;
      union { ushort_t u[8]; bf16x8 v; } afr;
      #pragma unroll
      for (int p = 0; p < 4; p++){
        uint32_t n2 = np[p], s2 = sp[p];
        float a0 = __uint_as_float(n2 << 16)          * __uint_as_float(s2 << 16);
        float a1 = __uint_as_float(n2 & 0xffff0000u)  * __uint_as_float(s2 & 0xffff0000u);
        afr.u[2*p]   = f2bf(a0);
        afr.u[2*p+1] = f2bf(a1);
      }
      #pragma unroll
      for (int t = 0; t < 8; t++){
        union { uint4 q4; bf16x8 v; } bfr;
        bfr.q4 = bfrag[(kt*8 + t)*64 + lane];
        acc[t] = __builtin_amdgcn_mfma_f32_16x16x32_bf16(afr.v, bfr.v, acc[t], 0, 0, 0);
      }
    }
    #pragma unroll
    for (int r = 0; r < 4; r++){
      float s = 0.f;
      #pragma unroll
      for (int t = 0; t < 8; t++) s += leaky(acc[t][r]) * w2v[t];
      s += __shfl_xor(s, 1, 64);
      s += __shfl_xor(s, 2, 64);
      s += __shfl_xor(s, 4, 64);
      s += __shfl_xor(s, 8, 64);
      if (m == 0) score[row_base + q*4 + r] = s;
    }
  }
}

// ---- MFMA out: relu(bias + concat(self,agg) @ w3) [+ addsrc -> f32] -------
// D = W3^T · X^T : A-frag = w3 from LDS (stationary), B-frag = per-row x.
// Lane holds x-row = lane&15; D gives that row's cols 16t+q*4+r (4 consecutive).
// MODE0: K=12, self=emb[idx[row]],  neigh=emb[nbr[row*12+k]]         -> outb
// MODE1: K=2,  self=emb[nbr[row]],  neigh=emb[adj_all[nbr[row]*2+k]] -> outb
// MODE2: K=12, self=selfsrc[row],   neigh=out1[row*12+k]             -> outf (f32, +addsrc)
template<int MODE>
__global__ __launch_bounds__(256) void out_mfma(
    const float* __restrict__ score, const int* __restrict__ idx,
    const int* __restrict__ nbr, const int* __restrict__ adj_all,
    const ushort_t* __restrict__ emb, const ushort_t* __restrict__ out1,
    const ushort_t* __restrict__ selfsrc,
    const ushort_t* __restrict__ w3, const ushort_t* __restrict__ bias,
    const ushort_t* __restrict__ addsrc,
    ushort_t* __restrict__ outb, float* __restrict__ outf, int nrows){
  constexpr int K = (MODE == 1) ? 2 : 12;
  __shared__ uint4 afrag[4096];   // 64 KB: [kt 0..7][t 0..7][lane] -> 8 bf16 of w3^T
  int tid = threadIdx.x;
  for (int i = tid; i < 4096; i += 256){
    int kt = i >> 9, rem = i & 511, t = rem >> 6, ln = rem & 63;
    int q = ln >> 4, c = ln & 15;
    union { ushort_t u[8]; uint4 q4; } e;
    #pragma unroll
    for (int j = 0; j < 8; j++)
      e.u[j] = w3[(32*kt + q*8 + j)*128 + 16*t + c];   // A[n=c][k] = w3[k][n]
    afrag[i] = e.q4;
  }
  __syncthreads();
  int lane = tid & 63, wave = tid >> 6;
  int mrow = lane & 15, q = lane >> 4;
  // bias: lane needs cols 16t+q*4+r
  float bv[8][4];
  #pragma unroll
  for (int t = 0; t < 8; t++){
    const ushort_t* bp = bias + 16*t + q*4;
    #pragma unroll
    for (int r = 0; r < 4; r++) bv[t][r] = bf2f(bp[r]);
  }

  for (int it = 0; it < 2; it++){
    int row_base = blockIdx.x*128 + it*64 + wave*16;
    int row = row_base + mrow;
    bool active = row < nrows;
    int rowc = active ? row : (nrows - 1);
    // self pointer
    const ushort_t* sptr;
    if (MODE == 0)      sptr = emb     + (size_t)idx[rowc]*D_;
    else if (MODE == 1) sptr = emb     + (size_t)nbr[rowc]*D_;
    else                sptr = selfsrc + (size_t)rowc*D_;
    // neighbor pointers
    const ushort_t* nptr[K];
    #pragma unroll
    for (int k = 0; k < K; k++){
      if (MODE == 0)      nptr[k] = emb  + (size_t)nbr[rowc*12 + k]*D_;
      else if (MODE == 1) nptr[k] = emb  + (size_t)adj_all[(size_t)nbr[rowc]*2 + k]*D_;
      else                nptr[k] = out1 + (size_t)(rowc*12 + k)*D_;
    }
    // softmax over K
    float att[K];
    {
      const float* sc = score + (size_t)rowc*K;
      float mx = -__builtin_inff();
      #pragma unroll
      for (int k = 0; k < K; k++){ att[k] = sc[k]; mx = fmaxf(mx, att[k]); }
      float ssum = 0.f;
      #pragma unroll
      for (int k = 0; k < K; k++){ att[k] = __expf(att[k] - mx); ssum += att[k]; }
      float inv = 1.f / ssum;
      #pragma unroll
      for (int k = 0; k < K; k++) att[k] *= inv;
    }

    f32x4 acc[8];
    #pragma unroll
    for (int t = 0; t < 8; t++) acc[t] = (f32x4){0.f,0.f,0.f,0.f};

    #pragma unroll
    for (int kt = 0; kt < 8; kt++){
      union { ushort_t u[8]; uint4 q4; bf16x8 v; } bfr;
      if (kt < 4){
        bfr.q4 = *(const uint4*)(sptr + kt*32 + q*8);
      } else {
        float g[8] = {0,0,0,0,0,0,0,0};
        #pragma unroll
        for (int k = 0; k < K; k++){
          uint4 nv = *(const uint4*)(nptr[k] + (kt-4)*32 + q*8);
          const uint32_t* np = (const uint32_t*)&nv;
          #pragma unroll
          for (int p = 0; p < 4; p++){
            g[2*p]   = fmaf(att[k], __uint_as_float(np[p] << 16),         g[2*p]);
            g[2*p+1] = fmaf(att[k], __uint_as_float(np[p] & 0xffff0000u), g[2*p+1]);
          }
        }
        #pragma unroll
        for (int j = 0; j < 8; j++) bfr.u[j] = f2bf(g[j]);
      }
      #pragma unroll
      for (int t = 0; t < 8; t++){
        union { uint4 q4; bf16x8 v; } af;
        af.q4 = afrag[(kt*8 + t)*64 + lane];
        acc[t] = __builtin_amdgcn_mfma_f32_16x16x32_bf16(af.v, bfr.v, acc[t], 0, 0, 0);
      }
    }
    // epilogue: lane writes row `row`, cols 16t+q*4+{0..3}
    if (active){
      #pragma unroll
      for (int t = 0; t < 8; t++){
        int col0 = 16*t + q*4;
        float v[4];
        #pragma unroll
        for (int r = 0; r < 4; r++) v[r] = fmaxf(acc[t][r] + bv[t][r], 0.f);
        if (MODE == 2){
          const ushort_t* ap = addsrc + (size_t)row*D_ + col0;
          #pragma unroll
          for (int r = 0; r < 4; r++) v[r] += bf2f(ap[r]);
          *(f32x4*)(outf + (size_t)row*D_ + col0) = (f32x4){v[0], v[1], v[2], v[3]};
        } else {
          union { ushort_t u[4]; uint2 d2; } pk;
          #pragma unroll
          for (int r = 0; r < 4; r++) pk.u[r] = f2bf(v[r]);
          *(uint2*)(outb + (size_t)row*D_ + col0) = pk.d2;
        }
      }
    }
  }
}

extern "C" void kernel_launch(void* const* d_in, const int* in_sizes, int n_in,
                              void* d_out, int out_size, void* d_ws, size_t ws_size,
                              hipStream_t stream) {
  const int* inputs    = (const int*)d_in[0];
  const int* adj       = (const int*)d_in[1];
  const int* mask_item = (const int*)d_in[2];
  const int* item      = (const int*)d_in[3];
  const int* first_adj = (const int*)d_in[4];    // neigh1 (B,600)
  const int* adj_all   = (const int*)d_in[5];    // (50000,2)

  // ---- ws layout ----
  char* ws = (char*)d_ws;
  size_t o = 0;
  int*      flag   = (int*)(ws + o);      o += 64;
  ushort_t* emb_b  = (ushort_t*)(ws + o); o += 12800000;  // 50000*128 bf16
  ushort_t* alocb  = (ushort_t*)(ws + o); o += 1024;      // 4*128
  ushort_t* gw1b   = (ushort_t*)(ws + o); o += 65536;     // 2*128*128
  ushort_t* gw2b   = (ushort_t*)(ws + o); o += 512;       // 2*128
  ushort_t* gw3b   = (ushort_t*)(ws + o); o += 131072;    // 2*256*128
  ushort_t* gbb    = (ushort_t*)(ws + o); o += 512;       // 2*128
  float*    sess_f = (float*)(ws + o);    o += 65536;     // 128*128 f32
  ushort_t* sessb  = (ushort_t*)(ws + o); o += 32768;     // 128*128 bf16
  ushort_t* hlb    = (ushort_t*)(ws + o); o += 1638400;   // 6400*128 bf16
  size_t fixed = o;
  // variable: out1c CHB*153600 + o0c CHB*12800 + score CHB*4800 = CHB*171200
  int CHB = 16;
  if      (ws_size >= fixed + (size_t)128*171200) CHB = 128;
  else if (ws_size >= fixed + (size_t)64 *171200) CHB = 64;
  else if (ws_size >= fixed + (size_t)32 *171200) CHB = 32;
  ushort_t* out1c = (ushort_t*)(ws + o);  o += (size_t)CHB*153600;
  ushort_t* o0c   = (ushort_t*)(ws + o);  o += (size_t)CHB*12800;
  float*    score = (float*)(ws + o);

  float* outp = (float*)d_out;   // output is f32 storage

  // ---- dtype normalize ----
  detect_kernel<<<1, 64, 0, stream>>>((const uint32_t*)d_in[6], flag);
  cvt_kernel<<<(6400000+255)/256, 256, 0, stream>>>(d_in[6],  emb_b, 6400000, flag);
  cvt_kernel<<<(512+255)/256,     256, 0, stream>>>(d_in[7],  alocb, 512,     flag);
  cvt_kernel<<<(32768+255)/256,   256, 0, stream>>>(d_in[8],  gw1b,  32768,   flag);
  cvt_kernel<<<(256+255)/256,     256, 0, stream>>>(d_in[9],  gw2b,  256,     flag);
  cvt_kernel<<<(65536+255)/256,   256, 0, stream>>>(d_in[10], gw3b,  65536,   flag);
  cvt_kernel<<<(256+255)/256,     256, 0, stream>>>(d_in[11], gbb,   256,     flag);

  sess_kernel <<<B_, 128, 0, stream>>>(item, mask_item, emb_b, sess_f, sessb);
  local_kernel<<<B_*S_, 128, 0, stream>>>(inputs, adj, emb_b, alocb, hlb);

  int nchunk = B_ / CHB;
  for (int c = 0; c < nchunk; c++){
    int b0 = c * CHB;
    const int* fadj  = first_adj + (size_t)b0 * 600;
    const ushort_t* sbc = sessb + (size_t)b0 * D_;
    ushort_t*  hlc   = hlb  + (size_t)b0 * 50 * D_;
    float*     outc  = outp + (size_t)b0 * 50 * D_;
    int nrA = CHB*50, nrB = CHB*600;

    // call A: hop-0 weights; scores CHB*600; out CHB*50 -> o0c (bf16)
    score_mfma<0><<<CHB*600/128, 256, 0, stream>>>(sbc, emb_b, fadj, adj_all, out1c,
                                                   gw1b, gw2b, score);
    out_mfma<0><<<(nrA + 127)/128, 256, 0, stream>>>(score, inputs + b0*50, fadj, adj_all,
                                                     emb_b, out1c, emb_b, gw3b, gbb,
                                                     nullptr, o0c, nullptr, nrA);
    // call B: hop-0 weights; scores CHB*1200; out CHB*600 -> out1c (bf16)
    score_mfma<1><<<CHB*1200/128, 256, 0, stream>>>(sbc, emb_b, fadj, adj_all, out1c,
                                                    gw1b, gw2b, score);
    out_mfma<1><<<(nrB + 127)/128, 256, 0, stream>>>(score, fadj, fadj, adj_all,
                                                     emb_b, out1c, emb_b, gw3b, gbb,
                                                     nullptr, out1c, nullptr, nrB);
    // call C: hop-1 weights; scores CHB*600; out CHB*50 -> d_out (f32, +h_local)
    score_mfma<2><<<CHB*600/128, 256, 0, stream>>>(sbc, emb_b, fadj, adj_all, out1c,
                                                   gw1b + 16384, gw2b + 128, score);
    out_mfma<2><<<(nrA + 127)/128, 256, 0, stream>>>(score, nullptr, fadj, adj_all,
                                                     emb_b, out1c, o0c, gw3b + 32768, gbb + 128,
                                                     hlc, nullptr, outc, nrA);
  }
}

// Round 11
// 220.967 us; speedup vs baseline: 5.8498x; 1.2183x over previous
//
#include <hip/hip_runtime.h>
#include <stdint.h>

typedef unsigned short ushort_t;
typedef __attribute__((ext_vector_type(8))) short bf16x8;   // 4 VGPRs, 8 bf16
typedef __attribute__((ext_vector_type(4))) float f32x4;    // MFMA C/D

#define B_   128
#define S_   50
#define D_   128
#define ALPHA_ 0.2f

__device__ __forceinline__ float bf2f(ushort_t u){
  return __uint_as_float(((uint32_t)u) << 16);
}
__device__ __forceinline__ ushort_t f2bf(float f){
  uint32_t x = __float_as_uint(f);
  x = (x + 0x7fffu + ((x >> 16) & 1u)) >> 16;
  return (ushort_t)x;
}
__device__ __forceinline__ float leaky(float x){ return x >= 0.f ? x : ALPHA_*x; }

// ---- detect: are float inputs bf16-packed (flag=1) or f32 (flag=0)? -------
__global__ void detect_kernel(const uint32_t* __restrict__ emb_raw, int* __restrict__ flag){
  if (threadIdx.x == 0 && blockIdx.x == 0){
    int ok = 1;
    for (int i = 0; i < 64; i++){
      uint32_t lo = emb_raw[i] & 0xffffu;
      uint32_t ex = (lo >> 7) & 0xFFu;
      if (!(lo == 0u || (ex >= 64u && ex <= 126u))) ok = 0;
    }
    *flag = ok;
  }
}

// ---- cvt_all: all six float tensors -> contiguous bf16 dst, 4 elems/thread -
// segments (elems): emb 6400000 | aloc 512 | gw1 32768 | gw2 256 | gw3 65536 | gb 256
__global__ void cvt_all(const void* __restrict__ p0, const void* __restrict__ p1,
                        const void* __restrict__ p2, const void* __restrict__ p3,
                        const void* __restrict__ p4, const void* __restrict__ p5,
                        ushort_t* __restrict__ dst, const int* __restrict__ flag){
  const int seg_end[6] = {6400000, 6400512, 6433280, 6433536, 6499072, 6499328};
  int base = (blockIdx.x*256 + threadIdx.x) * 4;
  if (base >= 6499328) return;
  int s = 0;
  while (base >= seg_end[s]) s++;
  int segbase = (s == 0) ? 0 : seg_end[s-1];
  const void* src = (s==0)?p0:(s==1)?p1:(s==2)?p2:(s==3)?p3:(s==4)?p4:p5;
  int off = base - segbase;
  union { ushort_t u[4]; uint2 d2; } o;
  if (*flag){
    o.d2 = *(const uint2*)((const ushort_t*)src + off);
  } else {
    float4 v = *(const float4*)((const float*)src + off);
    o.u[0] = f2bf(v.x); o.u[1] = f2bf(v.y); o.u[2] = f2bf(v.z); o.u[3] = f2bf(v.w);
  }
  *(uint2*)(dst + base) = o.d2;
}

// ---- sess: masked mean of item embeddings -> bf16 (B,D) -------------------
__global__ void sess_kernel(const int* __restrict__ item, const int* __restrict__ mask,
                            const ushort_t* __restrict__ emb, ushort_t* __restrict__ sessb){
  int b = blockIdx.x, d = threadIdx.x;
  float acc = 0.f, den = 0.f;
  for (int s = 0; s < S_; s++){
    float fm = (float)mask[b*S_ + s];
    int id = item[b*S_ + s];
    acc += fm * bf2f(emb[(size_t)id*D_ + d]);
    den += fm;
  }
  sessb[b*D_ + d] = f2bf(acc / den);
}

// ---- local attention via MFMA: one block per b (4 waves; wave w = k=w) ----
// E_w = (h .* a_w) @ h^T ; att[i][j] = leaky(E_{adj[i][j]-1}) or -9e15;
// softmax rows; h_local = att @ h.
__global__ __launch_bounds__(256) void local_mfma(
    const int* __restrict__ inputs, const int* __restrict__ adj,
    const ushort_t* __restrict__ emb, const ushort_t* __restrict__ alocb,
    ushort_t* __restrict__ hlb){
  __shared__ ushort_t hS[64][136];   // h[j][d], row stride 272B (16B-aligned)
  __shared__ ushort_t hT[128][72];   // h^T[d][j], row stride 144B
  __shared__ float    attS[64][68];  // att[i][j], row stride 272B
  __shared__ int      sids[64];
  int b = blockIdx.x;
  int tid = threadIdx.x;
  if (tid < 64) sids[tid] = (tid < S_) ? inputs[b*S_ + tid] : 0;
  __syncthreads();
  for (int idx = tid; idx < 64*128; idx += 256){
    int j = idx >> 7, d = idx & 127;
    ushort_t v = 0;
    if (j < S_) v = emb[(size_t)sids[j]*D_ + d];
    hS[j][d] = v;
    hT[d][j] = v;
  }
  for (int idx = tid; idx < 64*64; idx += 256)
    attS[idx >> 6][idx & 63] = -9.0e15f;
  __syncthreads();

  int lane = tid & 63, wv = tid >> 6;
  int q = lane >> 4, c = lane & 15;

  // ---- E = (h .* a_wv) @ h^T ----
  f32x4 Eacc[4][4];
  #pragma unroll
  for (int mi = 0; mi < 4; mi++)
    #pragma unroll
    for (int ni = 0; ni < 4; ni++) Eacc[mi][ni] = (f32x4){0.f,0.f,0.f,0.f};
  #pragma unroll
  for (int kt = 0; kt < 4; kt++){
    uint4 av = *(const uint4*)(alocb + wv*D_ + kt*32 + q*8);
    const uint32_t* ap = (const uint32_t*)&av;
    union { ushort_t u[8]; bf16x8 v; } afr[4];
    #pragma unroll
    for (int mi = 0; mi < 4; mi++){
      uint4 hv = *(const uint4*)(&hS[mi*16 + c][kt*32 + q*8]);
      const uint32_t* hp = (const uint32_t*)&hv;
      #pragma unroll
      for (int p = 0; p < 4; p++){
        float x0 = __uint_as_float(hp[p] << 16)         * __uint_as_float(ap[p] << 16);
        float x1 = __uint_as_float(hp[p] & 0xffff0000u) * __uint_as_float(ap[p] & 0xffff0000u);
        afr[mi].u[2*p]   = f2bf(x0);
        afr[mi].u[2*p+1] = f2bf(x1);
      }
    }
    #pragma unroll
    for (int ni = 0; ni < 4; ni++){
      union { uint4 q4; bf16x8 v; } bfr;
      bfr.q4 = *(const uint4*)(&hS[ni*16 + c][kt*32 + q*8]);  // B[k=d][n=j]=h[j][d]
      #pragma unroll
      for (int mi = 0; mi < 4; mi++)
        Eacc[mi][ni] = __builtin_amdgcn_mfma_f32_16x16x32_bf16(afr[mi].v, bfr.v, Eacc[mi][ni], 0,0,0);
    }
  }
  // scatter into attS where adj == wv+1
  const int* adjb = adj + (size_t)b*S_*S_;
  #pragma unroll
  for (int mi = 0; mi < 4; mi++){
    #pragma unroll
    for (int ni = 0; ni < 4; ni++){
      int j = ni*16 + c;
      #pragma unroll
      for (int r = 0; r < 4; r++){
        int i = mi*16 + q*4 + r;
        if (i < S_ && j < S_){
          int kk = adjb[i*S_ + j];
          if (kk == wv + 1) attS[i][j] = leaky(Eacc[mi][ni][r]);
        }
      }
    }
  }
  __syncthreads();
  // softmax per row (threads 0..63)
  if (tid < 64){
    int i = tid;
    if (i < S_){
      float mx = -__builtin_inff();
      for (int j = 0; j < S_; j++) mx = fmaxf(mx, attS[i][j]);
      float s = 0.f;
      for (int j = 0; j < S_; j++){ float e = __expf(attS[i][j] - mx); attS[i][j] = e; s += e; }
      float inv = 1.f / s;
      for (int j = 0; j < S_; j++) attS[i][j] *= inv;
      for (int j = S_; j < 64; j++) attS[i][j] = 0.f;
    } else {
      for (int j = 0; j < 64; j++) attS[i][j] = 0.f;
    }
  }
  __syncthreads();
  // ---- h_local = att @ h ; wave wv covers d-tiles {2wv, 2wv+1} ----
  f32x4 Pacc[4][2];
  #pragma unroll
  for (int mi = 0; mi < 4; mi++){ Pacc[mi][0] = (f32x4){0.f,0.f,0.f,0.f}; Pacc[mi][1] = (f32x4){0.f,0.f,0.f,0.f}; }
  #pragma unroll
  for (int kt = 0; kt < 2; kt++){
    union { ushort_t u[8]; bf16x8 v; } afr[4];
    #pragma unroll
    for (int mi = 0; mi < 4; mi++){
      const float* arow = &attS[mi*16 + c][kt*32 + q*8];
      #pragma unroll
      for (int j = 0; j < 8; j++) afr[mi].u[j] = f2bf(arow[j]);
    }
    #pragma unroll
    for (int nn = 0; nn < 2; nn++){
      int ni = 2*wv + nn;
      union { uint4 q4; bf16x8 v; } bfr;
      bfr.q4 = *(const uint4*)(&hT[ni*16 + c][kt*32 + q*8]);  // B[k=j][n=d]=hT[d][j]
      #pragma unroll
      for (int mi = 0; mi < 4; mi++)
        Pacc[mi][nn] = __builtin_amdgcn_mfma_f32_16x16x32_bf16(afr[mi].v, bfr.v, Pacc[mi][nn], 0,0,0);
    }
  }
  #pragma unroll
  for (int mi = 0; mi < 4; mi++){
    #pragma unroll
    for (int nn = 0; nn < 2; nn++){
      int d = (2*wv + nn)*16 + c;
      #pragma unroll
      for (int r = 0; r < 4; r++){
        int i = mi*16 + q*4 + r;
        if (i < S_) hlb[((size_t)b*S_ + i)*D_ + d] = f2bf(Pacc[mi][nn][r]);
      }
    }
  }
}

// ---- merged score A+B: rows [0,nA) A-mode, [nA,3nA) B-mode ---------------
__global__ __launch_bounds__(256) void score_mfma_ab(
    const ushort_t* __restrict__ sessb, const ushort_t* __restrict__ emb,
    const int* __restrict__ neigh1, const int* __restrict__ adj_all,
    const ushort_t* __restrict__ w1, const ushort_t* __restrict__ w2,
    float* __restrict__ score, int nA){
  __shared__ uint4 bfrag[2048];      // 32 KB w1 B-frags
  int tid = threadIdx.x;
  for (int idx = tid; idx < 2048; idx += 256){
    int kt = idx >> 9, rem = idx & 511, t = rem >> 6, ln = rem & 63;
    int qq = ln >> 4, cc = ln & 15;
    union { ushort_t u[8]; uint4 q4; } e;
    #pragma unroll
    for (int j = 0; j < 8; j++)
      e.u[j] = w1[(32*kt + qq*8 + j)*128 + 16*t + cc];
    bfrag[idx] = e.q4;
  }
  __syncthreads();
  int lane = tid & 63, wave = tid >> 6;
  int m = lane & 15, q = lane >> 4;
  float w2v[8];
  #pragma unroll
  for (int t = 0; t < 8; t++) w2v[t] = bf2f(w2[16*t + m]);

  for (int it = 0; it < 2; it++){
    int row_base = blockIdx.x*128 + it*64 + wave*16;
    int row = row_base + m;
    const ushort_t* nrow; int b;
    if (row < nA){
      nrow = emb + (size_t)neigh1[row]*D_;
      b = row / 600;
    } else {
      int r2 = row - nA;
      nrow = emb + (size_t)adj_all[(size_t)neigh1[r2>>1]*2 + (r2&1)]*D_;
      b = r2 / 1200;
    }
    const ushort_t* srow = sessb + (size_t)b*D_;

    f32x4 acc[8];
    #pragma unroll
    for (int t = 0; t < 8; t++) acc[t] = (f32x4){0.f,0.f,0.f,0.f};
    #pragma unroll
    for (int kt = 0; kt < 4; kt++){
      uint4 nv = *(const uint4*)(nrow + kt*32 + q*8);
      uint4 sv = *(const uint4*)(srow + kt*32 + q*8);
      const uint32_t* np = (const uint32_t*)&nv;
      const uint32_t* sp = (const uint32_t*)&sv;
      union { ushort_t u[8]; bf16x8 v; } afr;
      #pragma unroll
      for (int p = 0; p < 4; p++){
        uint32_t n2 = np[p], s2 = sp[p];
        float a0 = __uint_as_float(n2 << 16)          * __uint_as_float(s2 << 16);
        float a1 = __uint_as_float(n2 & 0xffff0000u)  * __uint_as_float(s2 & 0xffff0000u);
        afr.u[2*p]   = f2bf(a0);
        afr.u[2*p+1] = f2bf(a1);
      }
      #pragma unroll
      for (int t = 0; t < 8; t++){
        union { uint4 q4; bf16x8 v; } bfr;
        bfr.q4 = bfrag[(kt*8 + t)*64 + lane];
        acc[t] = __builtin_amdgcn_mfma_f32_16x16x32_bf16(afr.v, bfr.v, acc[t], 0, 0, 0);
      }
    }
    #pragma unroll
    for (int r = 0; r < 4; r++){
      float s = 0.f;
      #pragma unroll
      for (int t = 0; t < 8; t++) s += leaky(acc[t][r]) * w2v[t];
      s += __shfl_xor(s, 1, 64);
      s += __shfl_xor(s, 2, 64);
      s += __shfl_xor(s, 4, 64);
      s += __shfl_xor(s, 8, 64);
      if (m == 0) score[row_base + q*4 + r] = s;
    }
  }
}

// ---- score C: neigh = out1[row] -------------------------------------------
__global__ __launch_bounds__(256) void score_mfma_c(
    const ushort_t* __restrict__ sessb, const ushort_t* __restrict__ out1,
    const ushort_t* __restrict__ w1, const ushort_t* __restrict__ w2,
    float* __restrict__ score){
  __shared__ uint4 bfrag[2048];
  int tid = threadIdx.x;
  for (int idx = tid; idx < 2048; idx += 256){
    int kt = idx >> 9, rem = idx & 511, t = rem >> 6, ln = rem & 63;
    int qq = ln >> 4, cc = ln & 15;
    union { ushort_t u[8]; uint4 q4; } e;
    #pragma unroll
    for (int j = 0; j < 8; j++)
      e.u[j] = w1[(32*kt + qq*8 + j)*128 + 16*t + cc];
    bfrag[idx] = e.q4;
  }
  __syncthreads();
  int lane = tid & 63, wave = tid >> 6;
  int m = lane & 15, q = lane >> 4;
  float w2v[8];
  #pragma unroll
  for (int t = 0; t < 8; t++) w2v[t] = bf2f(w2[16*t + m]);
  for (int it = 0; it < 2; it++){
    int row_base = blockIdx.x*128 + it*64 + wave*16;
    int row = row_base + m;
    const ushort_t* nrow = out1 + (size_t)row*D_;
    int b = row / 600;
    const ushort_t* srow = sessb + (size_t)b*D_;
    f32x4 acc[8];
    #pragma unroll
    for (int t = 0; t < 8; t++) acc[t] = (f32x4){0.f,0.f,0.f,0.f};
    #pragma unroll
    for (int kt = 0; kt < 4; kt++){
      uint4 nv = *(const uint4*)(nrow + kt*32 + q*8);
      uint4 sv = *(const uint4*)(srow + kt*32 + q*8);
      const uint32_t* np = (const uint32_t*)&nv;
      const uint32_t* sp = (const uint32_t*)&sv;
      union { ushort_t u[8]; bf16x8 v; } afr;
      #pragma unroll
      for (int p = 0; p < 4; p++){
        uint32_t n2 = np[p], s2 = sp[p];
        float a0 = __uint_as_float(n2 << 16)          * __uint_as_float(s2 << 16);
        float a1 = __uint_as_float(n2 & 0xffff0000u)  * __uint_as_float(s2 & 0xffff0000u);
        afr.u[2*p]   = f2bf(a0);
        afr.u[2*p+1] = f2bf(a1);
      }
      #pragma unroll
      for (int t = 0; t < 8; t++){
        union { uint4 q4; bf16x8 v; } bfr;
        bfr.q4 = bfrag[(kt*8 + t)*64 + lane];
        acc[t] = __builtin_amdgcn_mfma_f32_16x16x32_bf16(afr.v, bfr.v, acc[t], 0, 0, 0);
      }
    }
    #pragma unroll
    for (int r = 0; r < 4; r++){
      float s = 0.f;
      #pragma unroll
      for (int t = 0; t < 8; t++) s += leaky(acc[t][r]) * w2v[t];
      s += __shfl_xor(s, 1, 64);
      s += __shfl_xor(s, 2, 64);
      s += __shfl_xor(s, 4, 64);
      s += __shfl_xor(s, 8, 64);
      if (m == 0) score[row_base + q*4 + r] = s;
    }
  }
}

// ---- shared out helpers ---------------------------------------------------
template<int K>
__device__ __forceinline__ void softmaxK(const float* __restrict__ sc, float att[K]){
  float mx = -__builtin_inff();
  #pragma unroll
  for (int k = 0; k < K; k++){ att[k] = sc[k]; mx = fmaxf(mx, att[k]); }
  float s = 0.f;
  #pragma unroll
  for (int k = 0; k < K; k++){ att[k] = __expf(att[k] - mx); s += att[k]; }
  float inv = 1.f / s;
  #pragma unroll
  for (int k = 0; k < K; k++) att[k] *= inv;
}

template<int K>
__device__ __forceinline__ void out_tile(
    int lane, const uint4* __restrict__ afrag,
    const ushort_t* __restrict__ sptr, const ushort_t* const nptr[K],
    const float att[K], f32x4 acc[8]){
  int q = lane >> 4;
  #pragma unroll
  for (int kt = 0; kt < 8; kt++){
    union { ushort_t u[8]; uint4 q4; bf16x8 v; } bfr;
    if (kt < 4){
      bfr.q4 = *(const uint4*)(sptr + kt*32 + q*8);
    } else {
      float g[8] = {0,0,0,0,0,0,0,0};
      #pragma unroll
      for (int k = 0; k < K; k++){
        uint4 nv = *(const uint4*)(nptr[k] + (kt-4)*32 + q*8);
        const uint32_t* np = (const uint32_t*)&nv;
        #pragma unroll
        for (int p = 0; p < 4; p++){
          g[2*p]   = fmaf(att[k], __uint_as_float(np[p] << 16),         g[2*p]);
          g[2*p+1] = fmaf(att[k], __uint_as_float(np[p] & 0xffff0000u), g[2*p+1]);
        }
      }
      #pragma unroll
      for (int j = 0; j < 8; j++) bfr.u[j] = f2bf(g[j]);
    }
    #pragma unroll
    for (int t = 0; t < 8; t++){
      union { uint4 q4; bf16x8 v; } af;
      af.q4 = afrag[(kt*8 + t)*64 + lane];
      acc[t] = __builtin_amdgcn_mfma_f32_16x16x32_bf16(af.v, bfr.v, acc[t], 0, 0, 0);
    }
  }
}

// ---- merged out A+B: rows [0,nA) A (K=12 -> o0c), [nA,nTot) B (K=2 -> out1c)
__global__ __launch_bounds__(256) void out_mfma_ab(
    const float* __restrict__ score, const int* __restrict__ idx,
    const int* __restrict__ nbr, const int* __restrict__ adj_all,
    const ushort_t* __restrict__ emb,
    const ushort_t* __restrict__ w3, const ushort_t* __restrict__ bias,
    ushort_t* __restrict__ o0c, ushort_t* __restrict__ out1c,
    int nA, int nTot, int scoreBbase){
  __shared__ uint4 afrag[4096];   // 64 KB w3^T A-frags
  int tid = threadIdx.x;
  for (int i = tid; i < 4096; i += 256){
    int kt = i >> 9, rem = i & 511, t = rem >> 6, ln = rem & 63;
    int qq = ln >> 4, cc = ln & 15;
    union { ushort_t u[8]; uint4 q4; } e;
    #pragma unroll
    for (int j = 0; j < 8; j++)
      e.u[j] = w3[(32*kt + qq*8 + j)*128 + 16*t + cc];
    afrag[i] = e.q4;
  }
  __syncthreads();
  int lane = tid & 63, wave = tid >> 6;
  int mrow = lane & 15, q = lane >> 4;
  float bv[8][4];
  #pragma unroll
  for (int t = 0; t < 8; t++){
    const ushort_t* bp = bias + 16*t + q*4;
    #pragma unroll
    for (int r = 0; r < 4; r++) bv[t][r] = bf2f(bp[r]);
  }
  for (int it = 0; it < 2; it++){
    int row_base = blockIdx.x*128 + it*64 + wave*16;
    int row = row_base + mrow;
    bool active = row < nTot;
    int rowc = active ? row : (nTot - 1);
    bool isA = rowc < nA;
    f32x4 acc[8];
    #pragma unroll
    for (int t = 0; t < 8; t++) acc[t] = (f32x4){0.f,0.f,0.f,0.f};
    if (isA){
      const ushort_t* sptr = emb + (size_t)idx[rowc]*D_;
      const ushort_t* nptr[12];
      #pragma unroll
      for (int k = 0; k < 12; k++) nptr[k] = emb + (size_t)nbr[rowc*12 + k]*D_;
      float att[12];
      softmaxK<12>(score + (size_t)rowc*12, att);
      out_tile<12>(lane, afrag, sptr, nptr, att, acc);
    } else {
      int rB = rowc - nA;
      const ushort_t* sptr = emb + (size_t)nbr[rB]*D_;
      const ushort_t* nptr[2];
      #pragma unroll
      for (int k = 0; k < 2; k++) nptr[k] = emb + (size_t)adj_all[(size_t)nbr[rB]*2 + k]*D_;
      float att[2];
      softmaxK<2>(score + scoreBbase + (size_t)rB*2, att);
      out_tile<2>(lane, afrag, sptr, nptr, att, acc);
    }
    if (active){
      ushort_t* dst = isA ? (o0c + (size_t)row*D_) : (out1c + (size_t)(row - nA)*D_);
      #pragma unroll
      for (int t = 0; t < 8; t++){
        int col0 = 16*t + q*4;
        union { ushort_t u[4]; uint2 d2; } pk;
        #pragma unroll
        for (int r = 0; r < 4; r++) pk.u[r] = f2bf(fmaxf(acc[t][r] + bv[t][r], 0.f));
        *(uint2*)(dst + col0) = pk.d2;
      }
    }
  }
}

// ---- out C: self=o0c[row], neigh=out1[row*12+k], +addsrc, f32 out ---------
__global__ __launch_bounds__(256) void out_mfma_c(
    const float* __restrict__ score, const ushort_t* __restrict__ out1,
    const ushort_t* __restrict__ selfsrc,
    const ushort_t* __restrict__ w3, const ushort_t* __restrict__ bias,
    const ushort_t* __restrict__ addsrc, float* __restrict__ outf, int nrows){
  __shared__ uint4 afrag[4096];
  int tid = threadIdx.x;
  for (int i = tid; i < 4096; i += 256){
    int kt = i >> 9, rem = i & 511, t = rem >> 6, ln = rem & 63;
    int qq = ln >> 4, cc = ln & 15;
    union { ushort_t u[8]; uint4 q4; } e;
    #pragma unroll
    for (int j = 0; j < 8; j++)
      e.u[j] = w3[(32*kt + qq*8 + j)*128 + 16*t + cc];
    afrag[i] = e.q4;
  }
  __syncthreads();
  int lane = tid & 63, wave = tid >> 6;
  int mrow = lane & 15, q = lane >> 4;
  float bv[8][4];
  #pragma unroll
  for (int t = 0; t < 8; t++){
    const ushort_t* bp = bias + 16*t + q*4;
    #pragma unroll
    for (int r = 0; r < 4; r++) bv[t][r] = bf2f(bp[r]);
  }
  for (int it = 0; it < 2; it++){
    int row_base = blockIdx.x*128 + it*64 + wave*16;
    int row = row_base + mrow;
    bool active = row < nrows;
    int rowc = active ? row : (nrows - 1);
    const ushort_t* sptr = selfsrc + (size_t)rowc*D_;
    const ushort_t* nptr[12];
    #pragma unroll
    for (int k = 0; k < 12; k++) nptr[k] = out1 + (size_t)(rowc*12 + k)*D_;
    float att[12];
    softmaxK<12>(score + (size_t)rowc*12, att);
    f32x4 acc[8];
    #pragma unroll
    for (int t = 0; t < 8; t++) acc[t] = (f32x4){0.f,0.f,0.f,0.f};
    out_tile<12>(lane, afrag, sptr, nptr, att, acc);
    if (active){
      #pragma unroll
      for (int t = 0; t < 8; t++){
        int col0 = 16*t + q*4;
        float v[4];
        const ushort_t* ap = addsrc + (size_t)row*D_ + col0;
        #pragma unroll
        for (int r = 0; r < 4; r++)
          v[r] = fmaxf(acc[t][r] + bv[t][r], 0.f) + bf2f(ap[r]);
        *(f32x4*)(outf + (size_t)row*D_ + col0) = (f32x4){v[0], v[1], v[2], v[3]};
      }
    }
  }
}

extern "C" void kernel_launch(void* const* d_in, const int* in_sizes, int n_in,
                              void* d_out, int out_size, void* d_ws, size_t ws_size,
                              hipStream_t stream) {
  const int* inputs    = (const int*)d_in[0];
  const int* adj       = (const int*)d_in[1];
  const int* mask_item = (const int*)d_in[2];
  const int* item      = (const int*)d_in[3];
  const int* first_adj = (const int*)d_in[4];    // neigh1 (B,600)
  const int* adj_all   = (const int*)d_in[5];    // (50000,2)

  // ---- ws layout (bf16 block is contiguous for cvt_all) ----
  char* ws = (char*)d_ws;
  size_t o = 0;
  int*      flag   = (int*)(ws + o);      o += 64;
  ushort_t* emb_b  = (ushort_t*)(ws + o); o += 12800000;  // 50000*128
  ushort_t* alocb  = (ushort_t*)(ws + o); o += 1024;      // 4*128
  ushort_t* gw1b   = (ushort_t*)(ws + o); o += 65536;     // 2*128*128
  ushort_t* gw2b   = (ushort_t*)(ws + o); o += 512;       // 2*128
  ushort_t* gw3b   = (ushort_t*)(ws + o); o += 131072;    // 2*256*128
  ushort_t* gbb    = (ushort_t*)(ws + o); o += 512;       // 2*128
  ushort_t* sessb  = (ushort_t*)(ws + o); o += 32768;     // 128*128
  ushort_t* hlb    = (ushort_t*)(ws + o); o += 1638400;   // 6400*128
  size_t fixed = o;
  // variable: out1c CHB*153600 + o0c CHB*12800 + score CHB*7200 = CHB*173600
  int CHB = 16;
  if      (ws_size >= fixed + (size_t)128*173600) CHB = 128;
  else if (ws_size >= fixed + (size_t)64 *173600) CHB = 64;
  else if (ws_size >= fixed + (size_t)32 *173600) CHB = 32;
  ushort_t* out1c = (ushort_t*)(ws + o);  o += (size_t)CHB*153600;
  ushort_t* o0c   = (ushort_t*)(ws + o);  o += (size_t)CHB*12800;
  float*    score = (float*)(ws + o);

  float* outp = (float*)d_out;   // output is f32 storage

  // ---- dtype normalize (2 launches) ----
  detect_kernel<<<1, 64, 0, stream>>>((const uint32_t*)d_in[6], flag);
  cvt_all<<<(6499328/4 + 255)/256, 256, 0, stream>>>(d_in[6], d_in[7], d_in[8], d_in[9],
                                                     d_in[10], d_in[11], emb_b, flag);

  sess_kernel<<<B_, 128, 0, stream>>>(item, mask_item, emb_b, sessb);
  local_mfma <<<B_, 256, 0, stream>>>(inputs, adj, emb_b, alocb, hlb);

  int nchunk = B_ / CHB;
  for (int c = 0; c < nchunk; c++){
    int b0 = c * CHB;
    const int* fadj  = first_adj + (size_t)b0 * 600;
    const ushort_t* sbc = sessb + (size_t)b0 * D_;
    ushort_t*  hlc   = hlb  + (size_t)b0 * 50 * D_;
    float*     outc  = outp + (size_t)b0 * 50 * D_;
    int nA600 = CHB*600, nA50 = CHB*50, nTot = CHB*650;

    // scores A (rows [0,nA600)) + B (rows [nA600, 3*nA600))
    score_mfma_ab<<<(3*nA600)/128, 256, 0, stream>>>(sbc, emb_b, fadj, adj_all,
                                                     gw1b, gw2b, score, nA600);
    // out A (-> o0c) + B (-> out1c)
    out_mfma_ab<<<(nTot + 127)/128, 256, 0, stream>>>(score, inputs + b0*50, fadj, adj_all,
                                                      emb_b, gw3b, gbb, o0c, out1c,
                                                      nA50, nTot, nA600);
    // scores C (rows [0,nA600))
    score_mfma_c<<<nA600/128, 256, 0, stream>>>(sbc, out1c, gw1b + 16384, gw2b + 128, score);
    // out C -> d_out (f32, + h_local)
    out_mfma_c<<<(nA50 + 127)/128, 256, 0, stream>>>(score, out1c, o0c,
                                                     gw3b + 32768, gbb + 128,
                                                     hlc, outc, nA50);
  }
}

// Round 13
// 218.110 us; speedup vs baseline: 5.9264x; 1.0131x over previous
//
#include <hip/hip_runtime.h>
#include <stdint.h>

typedef unsigned short ushort_t;
typedef __attribute__((ext_vector_type(8))) short bf16x8;   // 4 VGPRs, 8 bf16
typedef __attribute__((ext_vector_type(4))) float f32x4;    // MFMA C/D

#define B_   128
#define S_   50
#define D_   128
#define ALPHA_ 0.2f

__device__ __forceinline__ float bf2f(ushort_t u){
  return __uint_as_float(((uint32_t)u) << 16);
}
__device__ __forceinline__ ushort_t f2bf(float f){
  uint32_t x = __float_as_uint(f);
  x = (x + 0x7fffu + ((x >> 16) & 1u)) >> 16;
  return (ushort_t)x;
}
__device__ __forceinline__ float leaky(float x){ return x >= 0.f ? x : ALPHA_*x; }

// ---- detect: are float inputs bf16-packed (flag=1) or f32 (flag=0)? -------
__global__ void detect_kernel(const uint32_t* __restrict__ emb_raw, int* __restrict__ flag){
  if (threadIdx.x == 0 && blockIdx.x == 0){
    int ok = 1;
    for (int i = 0; i < 64; i++){
      uint32_t lo = emb_raw[i] & 0xffffu;
      uint32_t ex = (lo >> 7) & 0xFFu;
      if (!(lo == 0u || (ex >= 64u && ex <= 126u))) ok = 0;
    }
    *flag = ok;
  }
}

// ---- cvt_all: all six float tensors -> contiguous bf16 dst ----------------
__global__ void cvt_all(const void* __restrict__ p0, const void* __restrict__ p1,
                        const void* __restrict__ p2, const void* __restrict__ p3,
                        const void* __restrict__ p4, const void* __restrict__ p5,
                        ushort_t* __restrict__ dst, const int* __restrict__ flag){
  const int seg_end[6] = {6400000, 6400512, 6433280, 6433536, 6499072, 6499328};
  int base = (blockIdx.x*256 + threadIdx.x) * 4;
  if (base >= 6499328) return;
  int s = 0;
  while (base >= seg_end[s]) s++;
  int segbase = (s == 0) ? 0 : seg_end[s-1];
  const void* src = (s==0)?p0:(s==1)?p1:(s==2)?p2:(s==3)?p3:(s==4)?p4:p5;
  int off = base - segbase;
  union { ushort_t u[4]; uint2 d2; } o;
  if (*flag){
    o.d2 = *(const uint2*)((const ushort_t*)src + off);
  } else {
    float4 v = *(const float4*)((const float*)src + off);
    o.u[0] = f2bf(v.x); o.u[1] = f2bf(v.y); o.u[2] = f2bf(v.z); o.u[3] = f2bf(v.w);
  }
  *(uint2*)(dst + base) = o.d2;
}

// ---- sess: masked mean of item embeddings -> bf16 (B,D) -------------------
__global__ void sess_kernel(const int* __restrict__ item, const int* __restrict__ mask,
                            const ushort_t* __restrict__ emb, ushort_t* __restrict__ sessb){
  int b = blockIdx.x, d = threadIdx.x;
  float acc = 0.f, den = 0.f;
  for (int s = 0; s < S_; s++){
    float fm = (float)mask[b*S_ + s];
    int id = item[b*S_ + s];
    acc += fm * bf2f(emb[(size_t)id*D_ + d]);
    den += fm;
  }
  sessb[b*D_ + d] = f2bf(acc / den);
}

// ---- local attention via MFMA: one block per (b, mi) 16-row i-tile --------
// E_k = (h .* a_k) @ h^T (wave=k); att = softmax(select by adj); hl = att@h.
__global__ __launch_bounds__(256) void local_mfma2(
    const int* __restrict__ inputs, const int* __restrict__ adj,
    const ushort_t* __restrict__ emb, const ushort_t* __restrict__ alocb,
    ushort_t* __restrict__ hlb){
  __shared__ ushort_t hS[64][136];   // h[j][d], row stride 272B
  __shared__ float    attS[16][68];  // att tile
  __shared__ int      sids[64];
  int blk = blockIdx.x;
  int b  = blk >> 2;
  int mi = blk & 3;                  // i-tile: rows mi*16 .. mi*16+15
  int tid = threadIdx.x;
  if (tid < 64) sids[tid] = (tid < S_) ? inputs[b*S_ + tid] : 0;
  __syncthreads();
  for (int idx = tid; idx < 64*16; idx += 256){   // 64 rows x 16 chunks of 8 bf16 (16B)
    int j = idx >> 4, ch = idx & 15;
    uint4 v = {0u, 0u, 0u, 0u};
    if (j < S_) v = *(const uint4*)(emb + (size_t)sids[j]*D_ + ch*8);
    *(uint4*)(&hS[j][ch*8]) = v;
  }
  for (int idx = tid; idx < 16*64; idx += 256)
    attS[idx >> 6][idx & 63] = -9.0e15f;
  __syncthreads();

  int lane = tid & 63, wv = tid >> 6;       // wv = k
  int q = lane >> 4, c = lane & 15;

  // ---- E tile: A = (h .* a_wv) rows mi*16+c ; B = h rows ni*16+c ----
  f32x4 Eacc[4];
  #pragma unroll
  for (int ni = 0; ni < 4; ni++) Eacc[ni] = (f32x4){0.f,0.f,0.f,0.f};
  #pragma unroll
  for (int kt = 0; kt < 4; kt++){
    uint4 av = *(const uint4*)(alocb + wv*D_ + kt*32 + q*8);
    const uint32_t* ap = (const uint32_t*)&av;
    uint4 hv = *(const uint4*)(&hS[mi*16 + c][kt*32 + q*8]);
    const uint32_t* hp = (const uint32_t*)&hv;
    union { ushort_t u[8]; bf16x8 v; } afr;
    #pragma unroll
    for (int p = 0; p < 4; p++){
      float x0 = __uint_as_float(hp[p] << 16)         * __uint_as_float(ap[p] << 16);
      float x1 = __uint_as_float(hp[p] & 0xffff0000u) * __uint_as_float(ap[p] & 0xffff0000u);
      afr.u[2*p]   = f2bf(x0);
      afr.u[2*p+1] = f2bf(x1);
    }
    #pragma unroll
    for (int ni = 0; ni < 4; ni++){
      union { uint4 q4; bf16x8 v; } bfr;
      bfr.q4 = *(const uint4*)(&hS[ni*16 + c][kt*32 + q*8]);
      Eacc[ni] = __builtin_amdgcn_mfma_f32_16x16x32_bf16(afr.v, bfr.v, Eacc[ni], 0,0,0);
    }
  }
  // scatter: att[i][j] = leaky(E) where adj == wv+1
  const int* adjb = adj + (size_t)b*S_*S_;
  #pragma unroll
  for (int ni = 0; ni < 4; ni++){
    int j = ni*16 + c;
    #pragma unroll
    for (int r = 0; r < 4; r++){
      int i = mi*16 + q*4 + r;
      if (i < S_ && j < S_){
        int kk = adjb[i*S_ + j];
        if (kk == wv + 1) attS[q*4 + r][j] = leaky(Eacc[ni][r]);
      }
    }
  }
  __syncthreads();
  // softmax per row (threads 0..15)
  if (tid < 16){
    int i = mi*16 + tid;
    if (i < S_){
      float mx = -__builtin_inff();
      for (int j = 0; j < S_; j++) mx = fmaxf(mx, attS[tid][j]);
      float s = 0.f;
      for (int j = 0; j < S_; j++){ float e = __expf(attS[tid][j] - mx); attS[tid][j] = e; s += e; }
      float inv = 1.f / s;
      for (int j = 0; j < S_; j++) attS[tid][j] *= inv;
      for (int j = S_; j < 64; j++) attS[tid][j] = 0.f;
    } else {
      for (int j = 0; j < 64; j++) attS[tid][j] = 0.f;
    }
  }
  __syncthreads();
  // ---- P = att_tile @ h ; wave wv covers d-tiles {2wv, 2wv+1} ----
  f32x4 Pacc[2];
  Pacc[0] = (f32x4){0.f,0.f,0.f,0.f};
  Pacc[1] = (f32x4){0.f,0.f,0.f,0.f};
  #pragma unroll
  for (int kt = 0; kt < 2; kt++){
    union { ushort_t u[8]; bf16x8 v; } afr;
    const float* arow = &attS[c][kt*32 + q*8];
    #pragma unroll
    for (int j = 0; j < 8; j++) afr.u[j] = f2bf(arow[j]);
    #pragma unroll
    for (int nn = 0; nn < 2; nn++){
      int ni = 2*wv + nn;
      union { ushort_t u[8]; bf16x8 v; } bfr;
      #pragma unroll
      for (int jj = 0; jj < 8; jj++)
        bfr.u[jj] = hS[kt*32 + q*8 + jj][ni*16 + c];   // B[k=j][n=d]
      Pacc[nn] = __builtin_amdgcn_mfma_f32_16x16x32_bf16(afr.v, bfr.v, Pacc[nn], 0,0,0);
    }
  }
  #pragma unroll
  for (int nn = 0; nn < 2; nn++){
    int d = (2*wv + nn)*16 + c;
    #pragma unroll
    for (int r = 0; r < 4; r++){
      int i = mi*16 + q*4 + r;
      if (i < S_) hlb[((size_t)b*S_ + i)*D_ + d] = f2bf(Pacc[nn][r]);
    }
  }
}

// ---- merged score A+B: rows [0,nA) A-mode, [nA,3nA) B-mode ---------------
__global__ __launch_bounds__(256) void score_mfma_ab(
    const ushort_t* __restrict__ sessb, const ushort_t* __restrict__ emb,
    const int* __restrict__ neigh1, const int* __restrict__ adj_all,
    const ushort_t* __restrict__ w1, const ushort_t* __restrict__ w2,
    float* __restrict__ score, int nA){
  __shared__ uint4 bfrag[2048];      // 32 KB w1 B-frags
  int tid = threadIdx.x;
  for (int idx = tid; idx < 2048; idx += 256){
    int kt = idx >> 9, rem = idx & 511, t = rem >> 6, ln = rem & 63;
    int qq = ln >> 4, cc = ln & 15;
    union { ushort_t u[8]; uint4 q4; } e;
    #pragma unroll
    for (int j = 0; j < 8; j++)
      e.u[j] = w1[(32*kt + qq*8 + j)*128 + 16*t + cc];
    bfrag[idx] = e.q4;
  }
  __syncthreads();
  int lane = tid & 63, wave = tid >> 6;
  int m = lane & 15, q = lane >> 4;
  float w2v[8];
  #pragma unroll
  for (int t = 0; t < 8; t++) w2v[t] = bf2f(w2[16*t + m]);

  for (int it = 0; it < 2; it++){
    int row_base = blockIdx.x*128 + it*64 + wave*16;
    int row = row_base + m;
    const ushort_t* nrow; int b;
    if (row < nA){
      nrow = emb + (size_t)neigh1[row]*D_;
      b = row / 600;
    } else {
      int r2 = row - nA;
      nrow = emb + (size_t)adj_all[(size_t)neigh1[r2>>1]*2 + (r2&1)]*D_;
      b = r2 / 1200;
    }
    const ushort_t* srow = sessb + (size_t)b*D_;

    f32x4 acc[8];
    #pragma unroll
    for (int t = 0; t < 8; t++) acc[t] = (f32x4){0.f,0.f,0.f,0.f};
    #pragma unroll
    for (int kt = 0; kt < 4; kt++){
      uint4 nv = *(const uint4*)(nrow + kt*32 + q*8);
      uint4 sv = *(const uint4*)(srow + kt*32 + q*8);
      const uint32_t* np = (const uint32_t*)&nv;
      const uint32_t* sp = (const uint32_t*)&sv;
      union { ushort_t u[8]; bf16x8 v; } afr;
      #pragma unroll
      for (int p = 0; p < 4; p++){
        uint32_t n2 = np[p], s2 = sp[p];
        float a0 = __uint_as_float(n2 << 16)          * __uint_as_float(s2 << 16);
        float a1 = __uint_as_float(n2 & 0xffff0000u)  * __uint_as_float(s2 & 0xffff0000u);
        afr.u[2*p]   = f2bf(a0);
        afr.u[2*p+1] = f2bf(a1);
      }
      #pragma unroll
      for (int t = 0; t < 8; t++){
        union { uint4 q4; bf16x8 v; } bfr;
        bfr.q4 = bfrag[(kt*8 + t)*64 + lane];
        acc[t] = __builtin_amdgcn_mfma_f32_16x16x32_bf16(afr.v, bfr.v, acc[t], 0, 0, 0);
      }
    }
    #pragma unroll
    for (int r = 0; r < 4; r++){
      float s = 0.f;
      #pragma unroll
      for (int t = 0; t < 8; t++) s += leaky(acc[t][r]) * w2v[t];
      s += __shfl_xor(s, 1, 64);
      s += __shfl_xor(s, 2, 64);
      s += __shfl_xor(s, 4, 64);
      s += __shfl_xor(s, 8, 64);
      if (m == 0) score[row_base + q*4 + r] = s;
    }
  }
}

// ---- score C: neigh = out1[row] -------------------------------------------
__global__ __launch_bounds__(256) void score_mfma_c(
    const ushort_t* __restrict__ sessb, const ushort_t* __restrict__ out1,
    const ushort_t* __restrict__ w1, const ushort_t* __restrict__ w2,
    float* __restrict__ score){
  __shared__ uint4 bfrag[2048];
  int tid = threadIdx.x;
  for (int idx = tid; idx < 2048; idx += 256){
    int kt = idx >> 9, rem = idx & 511, t = rem >> 6, ln = rem & 63;
    int qq = ln >> 4, cc = ln & 15;
    union { ushort_t u[8]; uint4 q4; } e;
    #pragma unroll
    for (int j = 0; j < 8; j++)
      e.u[j] = w1[(32*kt + qq*8 + j)*128 + 16*t + cc];
    bfrag[idx] = e.q4;
  }
  __syncthreads();
  int lane = tid & 63, wave = tid >> 6;
  int m = lane & 15, q = lane >> 4;
  float w2v[8];
  #pragma unroll
  for (int t = 0; t < 8; t++) w2v[t] = bf2f(w2[16*t + m]);
  for (int it = 0; it < 2; it++){
    int row_base = blockIdx.x*128 + it*64 + wave*16;
    int row = row_base + m;
    const ushort_t* nrow = out1 + (size_t)row*D_;
    int b = row / 600;
    const ushort_t* srow = sessb + (size_t)b*D_;
    f32x4 acc[8];
    #pragma unroll
    for (int t = 0; t < 8; t++) acc[t] = (f32x4){0.f,0.f,0.f,0.f};
    #pragma unroll
    for (int kt = 0; kt < 4; kt++){
      uint4 nv = *(const uint4*)(nrow + kt*32 + q*8);
      uint4 sv = *(const uint4*)(srow + kt*32 + q*8);
      const uint32_t* np = (const uint32_t*)&nv;
      const uint32_t* sp = (const uint32_t*)&sv;
      union { ushort_t u[8]; bf16x8 v; } afr;
      #pragma unroll
      for (int p = 0; p < 4; p++){
        uint32_t n2 = np[p], s2 = sp[p];
        float a0 = __uint_as_float(n2 << 16)          * __uint_as_float(s2 << 16);
        float a1 = __uint_as_float(n2 & 0xffff0000u)  * __uint_as_float(s2 & 0xffff0000u);
        afr.u[2*p]   = f2bf(a0);
        afr.u[2*p+1] = f2bf(a1);
      }
      #pragma unroll
      for (int t = 0; t < 8; t++){
        union { uint4 q4; bf16x8 v; } bfr;
        bfr.q4 = bfrag[(kt*8 + t)*64 + lane];
        acc[t] = __builtin_amdgcn_mfma_f32_16x16x32_bf16(afr.v, bfr.v, acc[t], 0, 0, 0);
      }
    }
    #pragma unroll
    for (int r = 0; r < 4; r++){
      float s = 0.f;
      #pragma unroll
      for (int t = 0; t < 8; t++) s += leaky(acc[t][r]) * w2v[t];
      s += __shfl_xor(s, 1, 64);
      s += __shfl_xor(s, 2, 64);
      s += __shfl_xor(s, 4, 64);
      s += __shfl_xor(s, 8, 64);
      if (m == 0) score[row_base + q*4 + r] = s;
    }
  }
}

// ---- shared out helpers ---------------------------------------------------
template<int K>
__device__ __forceinline__ void softmaxK(const float* __restrict__ sc, float att[K]){
  float mx = -__builtin_inff();
  #pragma unroll
  for (int k = 0; k < K; k++){ att[k] = sc[k]; mx = fmaxf(mx, att[k]); }
  float s = 0.f;
  #pragma unroll
  for (int k = 0; k < K; k++){ att[k] = __expf(att[k] - mx); s += att[k]; }
  float inv = 1.f / s;
  #pragma unroll
  for (int k = 0; k < K; k++) att[k] *= inv;
}

// NT = number of 16-col output tiles this block computes (afrag has NT t's)
template<int K, int NT>
__device__ __forceinline__ void out_tile(
    int lane, const uint4* __restrict__ afrag,
    const ushort_t* __restrict__ sptr, const ushort_t* const nptr[K],
    const float att[K], f32x4 acc[NT]){
  int q = lane >> 4;
  #pragma unroll
  for (int kt = 0; kt < 8; kt++){
    union { ushort_t u[8]; uint4 q4; bf16x8 v; } bfr;
    if (kt < 4){
      bfr.q4 = *(const uint4*)(sptr + kt*32 + q*8);
    } else {
      float g[8] = {0,0,0,0,0,0,0,0};
      #pragma unroll
      for (int k = 0; k < K; k++){
        uint4 nv = *(const uint4*)(nptr[k] + (kt-4)*32 + q*8);
        const uint32_t* np = (const uint32_t*)&nv;
        #pragma unroll
        for (int p = 0; p < 4; p++){
          g[2*p]   = fmaf(att[k], __uint_as_float(np[p] << 16),         g[2*p]);
          g[2*p+1] = fmaf(att[k], __uint_as_float(np[p] & 0xffff0000u), g[2*p+1]);
        }
      }
      #pragma unroll
      for (int j = 0; j < 8; j++) bfr.u[j] = f2bf(g[j]);
    }
    #pragma unroll
    for (int t = 0; t < NT; t++){
      union { uint4 q4; bf16x8 v; } af;
      af.q4 = afrag[(kt*NT + t)*64 + lane];
      acc[t] = __builtin_amdgcn_mfma_f32_16x16x32_bf16(af.v, bfr.v, acc[t], 0, 0, 0);
    }
  }
}

// ---- merged out A+B, column-split: blockIdx.x = rb*2 + half ---------------
// half h computes output cols [h*64, h*64+64); 32 KB LDS -> 4 blocks/CU.
__global__ __launch_bounds__(256) void out_mfma_ab(
    const float* __restrict__ score, const int* __restrict__ idx,
    const int* __restrict__ nbr, const int* __restrict__ adj_all,
    const ushort_t* __restrict__ emb,
    const ushort_t* __restrict__ w3, const ushort_t* __restrict__ bias,
    ushort_t* __restrict__ o0c, ushort_t* __restrict__ out1c,
    int nA, int nTot, int scoreBbase){
  __shared__ uint4 afrag[2048];   // 32 KB: w3^T A-frags for 4 t-tiles
  int half = blockIdx.x & 1;
  int rb   = blockIdx.x >> 1;
  int tbase = half*4;
  int tid = threadIdx.x;
  for (int i = tid; i < 2048; i += 256){
    int kt = i >> 8, rem = i & 255, t = rem >> 6, ln = rem & 63;
    int qq = ln >> 4, cc = ln & 15;
    union { ushort_t u[8]; uint4 q4; } e;
    #pragma unroll
    for (int j = 0; j < 8; j++)
      e.u[j] = w3[(32*kt + qq*8 + j)*128 + 16*(tbase + t) + cc];
    afrag[i] = e.q4;
  }
  __syncthreads();
  int lane = tid & 63, wave = tid >> 6;
  int mrow = lane & 15, q = lane >> 4;
  float bv[4][4];
  #pragma unroll
  for (int t = 0; t < 4; t++){
    const ushort_t* bp = bias + 16*(tbase + t) + q*4;
    #pragma unroll
    for (int r = 0; r < 4; r++) bv[t][r] = bf2f(bp[r]);
  }
  for (int it = 0; it < 2; it++){
    int row_base = rb*128 + it*64 + wave*16;
    int row = row_base + mrow;
    bool active = row < nTot;
    int rowc = active ? row : (nTot - 1);
    bool isA = rowc < nA;
    f32x4 acc[4];
    #pragma unroll
    for (int t = 0; t < 4; t++) acc[t] = (f32x4){0.f,0.f,0.f,0.f};
    if (isA){
      const ushort_t* sptr = emb + (size_t)idx[rowc]*D_;
      const ushort_t* nptr[12];
      #pragma unroll
      for (int k = 0; k < 12; k++) nptr[k] = emb + (size_t)nbr[rowc*12 + k]*D_;
      float att[12];
      softmaxK<12>(score + (size_t)rowc*12, att);
      out_tile<12,4>(lane, afrag, sptr, nptr, att, acc);
    } else {
      int rB = rowc - nA;
      const ushort_t* sptr = emb + (size_t)nbr[rB]*D_;
      const ushort_t* nptr[2];
      #pragma unroll
      for (int k = 0; k < 2; k++) nptr[k] = emb + (size_t)adj_all[(size_t)nbr[rB]*2 + k]*D_;
      float att[2];
      softmaxK<2>(score + scoreBbase + (size_t)rB*2, att);
      out_tile<2,4>(lane, afrag, sptr, nptr, att, acc);
    }
    if (active){
      ushort_t* dst = isA ? (o0c + (size_t)row*D_) : (out1c + (size_t)(row - nA)*D_);
      #pragma unroll
      for (int t = 0; t < 4; t++){
        int col0 = 16*(tbase + t) + q*4;
        union { ushort_t u[4]; uint2 d2; } pk;
        #pragma unroll
        for (int r = 0; r < 4; r++) pk.u[r] = f2bf(fmaxf(acc[t][r] + bv[t][r], 0.f));
        *(uint2*)(dst + col0) = pk.d2;
      }
    }
  }
}

// ---- out C: self=o0c[row], neigh=out1[row*12+k], +addsrc, f32 out ---------
__global__ __launch_bounds__(256) void out_mfma_c(
    const float* __restrict__ score, const ushort_t* __restrict__ out1,
    const ushort_t* __restrict__ selfsrc,
    const ushort_t* __restrict__ w3, const ushort_t* __restrict__ bias,
    const ushort_t* __restrict__ addsrc, float* __restrict__ outf, int nrows){
  __shared__ uint4 afrag[4096];
  int tid = threadIdx.x;
  for (int i = tid; i < 4096; i += 256){
    int kt = i >> 9, rem = i & 511, t = rem >> 6, ln = rem & 63;
    int qq = ln >> 4, cc = ln & 15;
    union { ushort_t u[8]; uint4 q4; } e;
    #pragma unroll
    for (int j = 0; j < 8; j++)
      e.u[j] = w3[(32*kt + qq*8 + j)*128 + 16*t + cc];
    afrag[i] = e.q4;
  }
  __syncthreads();
  int lane = tid & 63, wave = tid >> 6;
  int mrow = lane & 15, q = lane >> 4;
  float bv[8][4];
  #pragma unroll
  for (int t = 0; t < 8; t++){
    const ushort_t* bp = bias + 16*t + q*4;
    #pragma unroll
    for (int r = 0; r < 4; r++) bv[t][r] = bf2f(bp[r]);
  }
  for (int it = 0; it < 2; it++){
    int row_base = blockIdx.x*128 + it*64 + wave*16;
    int row = row_base + mrow;
    bool active = row < nrows;
    int rowc = active ? row : (nrows - 1);
    const ushort_t* sptr = selfsrc + (size_t)rowc*D_;
    const ushort_t* nptr[12];
    #pragma unroll
    for (int k = 0; k < 12; k++) nptr[k] = out1 + (size_t)(rowc*12 + k)*D_;
    float att[12];
    softmaxK<12>(score + (size_t)rowc*12, att);
    f32x4 acc[8];
    #pragma unroll
    for (int t = 0; t < 8; t++) acc[t] = (f32x4){0.f,0.f,0.f,0.f};
    out_tile<12,8>(lane, afrag, sptr, nptr, att, acc);
    if (active){
      #pragma unroll
      for (int t = 0; t < 8; t++){
        int col0 = 16*t + q*4;
        float v[4];
        const ushort_t* ap = addsrc + (size_t)row*D_ + col0;
        #pragma unroll
        for (int r = 0; r < 4; r++)
          v[r] = fmaxf(acc[t][r] + bv[t][r], 0.f) + bf2f(ap[r]);
        *(f32x4*)(outf + (size_t)row*D_ + col0) = (f32x4){v[0], v[1], v[2], v[3]};
      }
    }
  }
}

extern "C" void kernel_launch(void* const* d_in, const int* in_sizes, int n_in,
                              void* d_out, int out_size, void* d_ws, size_t ws_size,
                              hipStream_t stream) {
  const int* inputs    = (const int*)d_in[0];
  const int* adj       = (const int*)d_in[1];
  const int* mask_item = (const int*)d_in[2];
  const int* item      = (const int*)d_in[3];
  const int* first_adj = (const int*)d_in[4];    // neigh1 (B,600)
  const int* adj_all   = (const int*)d_in[5];    // (50000,2)

  // ---- ws layout (bf16 block is contiguous for cvt_all) ----
  char* ws = (char*)d_ws;
  size_t o = 0;
  int*      flag   = (int*)(ws + o);      o += 64;
  ushort_t* emb_b  = (ushort_t*)(ws + o); o += 12800000;  // 50000*128
  ushort_t* alocb  = (ushort_t*)(ws + o); o += 1024;      // 4*128
  ushort_t* gw1b   = (ushort_t*)(ws + o); o += 65536;     // 2*128*128
  ushort_t* gw2b   = (ushort_t*)(ws + o); o += 512;       // 2*128
  ushort_t* gw3b   = (ushort_t*)(ws + o); o += 131072;    // 2*256*128
  ushort_t* gbb    = (ushort_t*)(ws + o); o += 512;       // 2*128
  ushort_t* sessb  = (ushort_t*)(ws + o); o += 32768;     // 128*128
  ushort_t* hlb    = (ushort_t*)(ws + o); o += 1638400;   // 6400*128
  size_t fixed = o;
  // variable: out1c CHB*153600 + o0c CHB*12800 + score CHB*7200 = CHB*173600
  int CHB = 16;
  if      (ws_size >= fixed + (size_t)128*173600) CHB = 128;
  else if (ws_size >= fixed + (size_t)64 *173600) CHB = 64;
  else if (ws_size >= fixed + (size_t)32 *173600) CHB = 32;
  ushort_t* out1c = (ushort_t*)(ws + o);  o += (size_t)CHB*153600;
  ushort_t* o0c   = (ushort_t*)(ws + o);  o += (size_t)CHB*12800;
  float*    score = (float*)(ws + o);

  float* outp = (float*)d_out;   // output is f32 storage

  // ---- dtype normalize (2 launches) ----
  detect_kernel<<<1, 64, 0, stream>>>((const uint32_t*)d_in[6], flag);
  cvt_all<<<(6499328/4 + 255)/256, 256, 0, stream>>>(d_in[6], d_in[7], d_in[8], d_in[9],
                                                     d_in[10], d_in[11], emb_b, flag);

  sess_kernel<<<B_, 128, 0, stream>>>(item, mask_item, emb_b, sessb);
  local_mfma2<<<B_*4, 256, 0, stream>>>(inputs, adj, emb_b, alocb, hlb);

  int nchunk = B_ / CHB;
  for (int c = 0; c < nchunk; c++){
    int b0 = c * CHB;
    const int* fadj  = first_adj + (size_t)b0 * 600;
    const ushort_t* sbc = sessb + (size_t)b0 * D_;
    ushort_t*  hlc   = hlb  + (size_t)b0 * 50 * D_;
    float*     outc  = outp + (size_t)b0 * 50 * D_;
    int nA600 = CHB*600, nA50 = CHB*50, nTot = CHB*650;

    // scores A (rows [0,nA600)) + B (rows [nA600, 3*nA600))
    score_mfma_ab<<<(3*nA600)/128, 256, 0, stream>>>(sbc, emb_b, fadj, adj_all,
                                                     gw1b, gw2b, score, nA600);
    // out A (-> o0c) + B (-> out1c), column-split
    out_mfma_ab<<<((nTot + 127)/128)*2, 256, 0, stream>>>(score, inputs + b0*50, fadj, adj_all,
                                                          emb_b, gw3b, gbb, o0c, out1c,
                                                          nA50, nTot, nA600);
    // scores C (rows [0,nA600))
    score_mfma_c<<<nA600/128, 256, 0, stream>>>(sbc, out1c, gw1b + 16384, gw2b + 128, score);
    // out C -> d_out (f32, + h_local)
    out_mfma_c<<<(nA50 + 127)/128, 256, 0, stream>>>(score, out1c, o0c,
                                                     gw3b + 32768, gbb + 128,
                                                     hlc, outc, nA50);
  }
}